// Round 3
// baseline (965.731 us; speedup 1.0000x reference)
//
#include <hip/hip_runtime.h>
#include <math.h>

// ---------------- workspace layout (float offsets) ----------------
#define WS_STATS 0         // 24 floats: [layer][S_r,S_i,S_j,S_k,Q_r,Q_i,Q_j,Q_k]
#define WS_W1    32        // 16*4*9   = 576      layout [s(4)][oc(16)][9]
#define WS_W2    640       // 64*16*9  = 9216     layout [ic(16)][oc(64)][9]
#define WS_W3    9856      // 128*64*9 = 73728    layout [ic(64)][oc(128)][9]
#define WS_WFC   83584     // 2048*16  = 32768
#define WS_POOL  116352    // 256*200  = 51200
#define WS_IDX   167552    // 256*3 ints
#define WS_OUT1  168448    // 256*16*32*32 = 4194304 (also OUT2)
#define WS_P1    4362752   // 256*16*16*16 = 1048576 (also P2)
#define WS_OUT3  5411328   // 256*128*8*8  = 2097152
#define WS_P3    7508480   // 256*128*4*4  = 524288

// Hamilton block table: T[a][b] -> (component, sign)
__device__ const int   d_TC[4][4] = {{0,1,2,3},{1,0,3,2},{2,3,0,1},{3,2,1,0}};
__device__ const float d_TS[4][4] = {{1.f,-1.f,-1.f,-1.f},{1.f,1.f,-1.f,1.f},
                                     {1.f,1.f,1.f,-1.f},{1.f,-1.f,1.f,1.f}};

// ---------------- prep: materialize W1/W2/W3/WFC, zero stats ----------------
__global__ __launch_bounds__(256) void prep_kernel(
    const float* l1r, const float* l1i, const float* l1j, const float* l1k,
    const float* l2r, const float* l2i, const float* l2j, const float* l2k,
    const float* l3r, const float* l3i, const float* l3j, const float* l3k,
    const float* fcr, const float* fci, const float* fcj, const float* fck,
    float* ws)
{
    int tid  = blockIdx.x * 256 + threadIdx.x;
    int nthr = gridDim.x * 256;
    if (tid < 24) ws[WS_STATS + tid] = 0.f;

    { // W1: [s(4)][oc(16)][9]
        const float* cp[4] = {l1r, l1i, l1j, l1k};
        for (int e = tid; e < 576; e += nthr) {
            int s = e / 144, rem = e % 144, oc = rem / 9, k = rem % 9;
            int p = oc >> 2, o = oc & 3;
            ws[WS_W1 + e] = d_TS[p][s] * cp[d_TC[p][s]][o * 9 + k];
        }
    }
    { // W2: [ic(16)][oc(64)][9]
        const float* cp[4] = {l2r, l2i, l2j, l2k};
        for (int e = tid; e < 9216; e += nthr) {
            int ic = e / 576, rem = e % 576, oc = rem / 9, k = rem % 9;
            int p = oc >> 4, o = oc & 15, s = ic >> 2, ii = ic & 3;
            ws[WS_W2 + e] = d_TS[p][s] * cp[d_TC[p][s]][(o * 4 + ii) * 9 + k];
        }
    }
    { // W3: [ic(64)][oc(128)][9]
        const float* cp[4] = {l3r, l3i, l3j, l3k};
        for (int e = tid; e < 73728; e += nthr) {
            int ic = e / 1152, rem = e % 1152, oc = rem / 9, k = rem % 9;
            int p = oc >> 5, o = oc & 31, s = ic >> 4, ii = ic & 15;
            ws[WS_W3 + e] = d_TS[p][s] * cp[d_TC[p][s]][(o * 16 + ii) * 9 + k];
        }
    }
    { // WFC: 2048 x 16 from (512,4) components
        const float* cp[4] = {fcr, fci, fcj, fck};
        for (int e = tid; e < 32768; e += nthr) {
            int R = e >> 4, C = e & 15;
            int p = R >> 9, rr = R & 511, q = C >> 2, cc = C & 3;
            ws[WS_WFC + e] = d_TS[q][p] * cp[d_TC[q][p]][rr * 4 + cc];
        }
    }
}

// ---------------- global average pool over 32x32 per (b,c) ----------------
__global__ __launch_bounds__(256) void mean_kernel(const float* __restrict__ x,
                                                   float* __restrict__ pooled)
{
    int bc = blockIdx.x;                    // 256*200
    int t  = threadIdx.x;
    const float4* src = reinterpret_cast<const float4*>(x + (size_t)bc * 1024);
    float4 v = src[t];
    float s = v.x + v.y + v.z + v.w;
    #pragma unroll
    for (int off = 32; off; off >>= 1) s += __shfl_xor(s, off, 64);
    __shared__ float red[4];
    if ((t & 63) == 0) red[t >> 6] = s;
    __syncthreads();
    if (t == 0) pooled[bc] = (red[0] + red[1] + red[2] + red[3]) * (1.0f / 1024.0f);
}

// ---------------- top-3 channels of w*pooled (tie -> lowest idx) ----------------
__global__ __launch_bounds__(64) void topk_kernel(const float* __restrict__ pooled,
                                                  const float* __restrict__ w_eca,
                                                  int* __restrict__ idx3)
{
    int b = blockIdx.x, lane = threadIdx.x;
    float w = w_eca[0];
    float v[4]; int c[4];
    #pragma unroll
    for (int i = 0; i < 4; i++) {
        int ch = lane + 64 * i;
        c[i] = ch;
        v[i] = (ch < 200) ? w * pooled[b * 200 + ch] : -INFINITY;
    }
    for (int k = 0; k < 3; k++) {
        float bv = -INFINITY; int bi = 0x3fffffff;
        #pragma unroll
        for (int i = 0; i < 4; i++)
            if (v[i] > bv || (v[i] == bv && c[i] < bi)) { bv = v[i]; bi = c[i]; }
        for (int off = 32; off; off >>= 1) {
            float ov = __shfl_xor(bv, off, 64);
            int   oi = __shfl_xor(bi, off, 64);
            if (ov > bv || (ov == bv && oi < bi)) { bv = ov; bi = oi; }
        }
        if (lane == 0) idx3[b * 3 + k] = bi;
        #pragma unroll
        for (int i = 0; i < 4; i++) if (c[i] == bi) v[i] = -INFINITY;
    }
}

// ---------------- conv1: gather top3 -> 3x3 conv (4->16ch, 32x32) + stats ----------------
// grid 1024 = 256 b * 4 row-groups of 8; thread = pixel.
__global__ __launch_bounds__(256, 4) void conv1_kernel(const float* __restrict__ x,
                                                       const int* __restrict__ idx3,
                                                       const float* __restrict__ W1,
                                                       const float* __restrict__ b1,
                                                       float* __restrict__ out1,
                                                       float* __restrict__ stats)
{
    __shared__ float smem[3][10][34];   // rows rg*8-1 .. rg*8+8, cols -1..32
    int blk = blockIdx.x;
    int b = blk >> 2, rg = blk & 3;
    int t = threadIdx.x;

    for (int i = t; i < 3 * 340; i += 256) {
        int s = i / 340, rem = i % 340, r = rem / 34, c = rem % 34;
        int row = rg * 8 + r - 1, col = c - 1;
        float v = 0.f;
        if (row >= 0 && row < 32 && col >= 0 && col < 32)
            v = x[((size_t)b * 200 + idx3[b * 3 + s]) * 1024 + row * 32 + col];
        smem[s][r][c] = v;
    }
    __syncthreads();

    int ry = t >> 5, col = t & 31;       // output row rg*8+ry, col
    float acc[16];
    #pragma unroll
    for (int oc = 0; oc < 16; oc++) acc[oc] = b1[oc];

    for (int s = 0; s < 3; s++) {
        float n[3][3];
        #pragma unroll
        for (int dy = 0; dy < 3; dy++)
            #pragma unroll
            for (int dx = 0; dx < 3; dx++)
                n[dy][dx] = smem[s][ry + dy][col + dx];
        const float* wb = W1 + (s + 1) * 144;   // [s+1][oc][9], uniform
        #pragma unroll
        for (int oc = 0; oc < 16; oc++) {
            const float* w = wb + oc * 9;
            float a = acc[oc];
            a = fmaf(w[0], n[0][0], a); a = fmaf(w[1], n[0][1], a); a = fmaf(w[2], n[0][2], a);
            a = fmaf(w[3], n[1][0], a); a = fmaf(w[4], n[1][1], a); a = fmaf(w[5], n[1][2], a);
            a = fmaf(w[6], n[2][0], a); a = fmaf(w[7], n[2][1], a); a = fmaf(w[8], n[2][2], a);
            acc[oc] = a;
        }
    }
    int y = rg * 8 + ry;
    float* outb = out1 + (size_t)b * 16 * 1024 + y * 32 + col;
    float s4[4] = {0,0,0,0}, q4[4] = {0,0,0,0};
    #pragma unroll
    for (int oc = 0; oc < 16; oc++) {
        float v = acc[oc];
        outb[oc * 1024] = v;
        s4[oc >> 2] += v;
        q4[oc >> 2] += v * v;
    }
    int lane = t & 63;
    #pragma unroll
    for (int g = 0; g < 4; g++) {
        float sv = s4[g], qv = q4[g];
        for (int off = 32; off; off >>= 1) { sv += __shfl_xor(sv, off, 64); qv += __shfl_xor(qv, off, 64); }
        if (lane == 0) { atomicAdd(&stats[g], sv); atomicAdd(&stats[4 + g], qv); }
    }
}

// ---------------- qbn + relu + 2x2 avg pool ----------------
template<int C, int H, int Cq>
__global__ __launch_bounds__(256) void bnpool_kernel(const float* __restrict__ in,
                                                     float* __restrict__ out,
                                                     const float* __restrict__ stats,
                                                     const float* __restrict__ gamma,
                                                     const float* __restrict__ beta,
                                                     float invN)
{
    constexpr int Ho = H / 2;
    int o = blockIdx.x * 256 + threadIdx.x;
    float mean[4]; float var = 0.f;
    #pragma unroll
    for (int g = 0; g < 4; g++) {
        float S = stats[g], Q = stats[4 + g];
        mean[g] = S * invN;
        var += Q - S * S * invN;
    }
    var *= invN;
    float inv = 1.0f / sqrtf(var + 1e-5f);

    int xq = o % Ho;
    int yq = (o / Ho) % Ho;
    int c  = (o / (Ho * Ho)) % C;
    int b  = o / (Ho * Ho * C);
    const float* base = in + ((size_t)((b * C + c) * H + 2 * yq)) * H + 2 * xq;
    float2 v01 = *reinterpret_cast<const float2*>(base);
    float2 v23 = *reinterpret_cast<const float2*>(base + H);
    int g = c / Cq, wv = c % Cq;
    float scale = gamma[wv] * inv;
    float sh = beta[c] - mean[g] * scale;
    float r0 = fmaxf(fmaf(v01.x, scale, sh), 0.f);
    float r1 = fmaxf(fmaf(v01.y, scale, sh), 0.f);
    float r2 = fmaxf(fmaf(v23.x, scale, sh), 0.f);
    float r3 = fmaxf(fmaf(v23.y, scale, sh), 0.f);
    out[o] = 0.25f * (r0 + r1 + r2 + r3);
}

// ---------------- conv2: 16->64 ch, 16x16, block = (batch, 8-oc group) ----------------
// grid 2048 = 256 b * 8 og; thread = pixel.
__global__ __launch_bounds__(256, 7) void conv2_kernel(const float* __restrict__ p1,
                                                       const float* __restrict__ W2,
                                                       const float* __restrict__ b2,
                                                       float* __restrict__ out2,
                                                       float* __restrict__ stats)
{
    __shared__ float smem[16][18][19];   // padded stride 19
    int blk = blockIdx.x;
    int b = blk >> 3, og = blk & 7;
    int oc0 = og * 8;
    int t = threadIdx.x;

    float* l = &smem[0][0][0];
    for (int i = t; i < 16 * 18 * 19; i += 256) l[i] = 0.f;
    __syncthreads();
    const float* src = p1 + (size_t)b * 4096;
    for (int i = t; i < 4096; i += 256) {
        int ic = i >> 8, rem = i & 255;
        smem[ic][(rem >> 4) + 1][(rem & 15) + 1] = src[i];
    }
    __syncthreads();

    int y = t >> 4, xx = t & 15;
    float acc[8];
    #pragma unroll
    for (int o = 0; o < 8; o++) acc[o] = b2[oc0 + o];

    for (int ic = 0; ic < 16; ic++) {
        float n[3][3];
        #pragma unroll
        for (int dy = 0; dy < 3; dy++)
            #pragma unroll
            for (int dx = 0; dx < 3; dx++)
                n[dy][dx] = smem[ic][y + dy][xx + dx];
        const float* wb = W2 + (ic * 64 + oc0) * 9;   // uniform, 72 contiguous dwords
        #pragma unroll
        for (int o = 0; o < 8; o++) {
            const float* w = wb + o * 9;
            float a = acc[o];
            a = fmaf(w[0], n[0][0], a); a = fmaf(w[1], n[0][1], a); a = fmaf(w[2], n[0][2], a);
            a = fmaf(w[3], n[1][0], a); a = fmaf(w[4], n[1][1], a); a = fmaf(w[5], n[1][2], a);
            a = fmaf(w[6], n[2][0], a); a = fmaf(w[7], n[2][1], a); a = fmaf(w[8], n[2][2], a);
            acc[o] = a;
        }
    }
    int lane = t & 63;
    float* outb = out2 + (size_t)b * 64 * 256 + oc0 * 256 + t;
    float sv = 0.f, qv = 0.f;
    #pragma unroll
    for (int o = 0; o < 8; o++) {
        float v = acc[o];
        outb[o * 256] = v;
        sv += v;
        qv += v * v;
    }
    int g = oc0 >> 4;   // quaternion group (16 ch per component)
    for (int off = 32; off; off >>= 1) { sv += __shfl_xor(sv, off, 64); qv += __shfl_xor(qv, off, 64); }
    if (lane == 0) { atomicAdd(&stats[g], sv); atomicAdd(&stats[4 + g], qv); }
}

// ---------------- conv3: 64->128 ch, 8x8, block = (batch, 16-oc group) ----------------
// grid 2048 = 256 b * 8 og; 4 waves split ic (16 each); reduce via reused LDS.
__global__ __launch_bounds__(256, 6) void conv3_kernel(const float* __restrict__ p2,
                                                       const float* __restrict__ W3,
                                                       const float* __restrict__ b3,
                                                       float* __restrict__ out3,
                                                       float* __restrict__ stats)
{
    __shared__ float smem[6400];   // input 64*10*10; later reused as partials [4][16][64]
    int blk = blockIdx.x;
    int b = blk >> 3, og = blk & 7;
    int oc0 = og * 16;
    int t = threadIdx.x;
    int wv = t >> 6, lane = t & 63;
    int wu = __builtin_amdgcn_readfirstlane(wv);
    int y = lane >> 3, xx = lane & 7;

    for (int i = t; i < 6400; i += 256) smem[i] = 0.f;
    __syncthreads();
    const float* src = p2 + (size_t)b * 4096;
    for (int i = t; i < 4096; i += 256) {
        int ic = i >> 6, px = i & 63;
        smem[ic * 100 + ((px >> 3) + 1) * 10 + (px & 7) + 1] = src[i];
    }
    __syncthreads();

    float acc[16];
    #pragma unroll
    for (int o = 0; o < 16; o++) acc[o] = 0.f;

    #pragma unroll 4
    for (int i = 0; i < 16; i++) {
        int icl = wv * 16 + i;              // lane-side LDS index
        float n[3][3];
        #pragma unroll
        for (int dy = 0; dy < 3; dy++)
            #pragma unroll
            for (int dx = 0; dx < 3; dx++)
                n[dy][dx] = smem[icl * 100 + (y + dy) * 10 + xx + dx];
        const float* wb = W3 + ((wu * 16 + i) * 128 + oc0) * 9;  // uniform, 144 dwords
        #pragma unroll
        for (int o = 0; o < 16; o++) {
            const float* w = wb + o * 9;
            float a = acc[o];
            a = fmaf(w[0], n[0][0], a); a = fmaf(w[1], n[0][1], a); a = fmaf(w[2], n[0][2], a);
            a = fmaf(w[3], n[1][0], a); a = fmaf(w[4], n[1][1], a); a = fmaf(w[5], n[1][2], a);
            a = fmaf(w[6], n[2][0], a); a = fmaf(w[7], n[2][1], a); a = fmaf(w[8], n[2][2], a);
            acc[o] = a;
        }
    }
    // reduce partials across the 4 ic-waves through LDS (input no longer needed)
    __syncthreads();
    #pragma unroll
    for (int o = 0; o < 16; o++) smem[wv * 1024 + o * 64 + lane] = acc[o];
    __syncthreads();

    // thread t -> oc = t>>4, 4 consecutive px
    int oc = t >> 4, px0 = (t & 15) * 4;
    float r[4];
    #pragma unroll
    for (int j = 0; j < 4; j++) {
        float s = b3[oc0 + oc];
        #pragma unroll
        for (int w = 0; w < 4; w++) s += smem[w * 1024 + oc * 64 + px0 + j];
        r[j] = s;
    }
    *reinterpret_cast<float4*>(out3 + ((size_t)b * 128 + oc0 + oc) * 64 + px0) =
        make_float4(r[0], r[1], r[2], r[3]);

    float sv = r[0] + r[1] + r[2] + r[3];
    float qv = r[0]*r[0] + r[1]*r[1] + r[2]*r[2] + r[3]*r[3];
    int g = oc0 >> 5;
    for (int off = 32; off; off >>= 1) { sv += __shfl_xor(sv, off, 64); qv += __shfl_xor(qv, off, 64); }
    if (lane == 0) { atomicAdd(&stats[g], sv); atomicAdd(&stats[4 + g], qv); }
}

// ---------------- fc: [256,2048] @ [2048,16] + b ----------------
__global__ __launch_bounds__(256) void fc_kernel(const float* __restrict__ p3,
                                                 const float* __restrict__ WFC,
                                                 const float* __restrict__ fcb,
                                                 float* __restrict__ out)
{
    int b = blockIdx.x, t = threadIdx.x;
    int col = t & 15, fr = t >> 4;
    const float* pb = p3 + (size_t)b * 2048;
    float s = 0.f;
    for (int i = 0; i < 128; i++) {
        int f = i * 16 + fr;
        s = fmaf(pb[f], WFC[f * 16 + col], s);
    }
    __shared__ float red[256];
    red[t] = s;
    __syncthreads();
    for (int st = 128; st >= 16; st >>= 1) {
        if (t < st) red[t] += red[t + st];
        __syncthreads();
    }
    if (t < 16) out[b * 16 + t] = red[t] + fcb[t];
}

// ---------------- launch ----------------
extern "C" void kernel_launch(void* const* d_in, const int* in_sizes, int n_in,
                              void* d_out, int out_size, void* d_ws, size_t ws_size,
                              hipStream_t stream)
{
    (void)in_sizes; (void)n_in; (void)out_size; (void)ws_size;
    const float* x     = (const float*)d_in[0];
    const float* w_eca = (const float*)d_in[1];
    const float* l1r = (const float*)d_in[2],  *l1i = (const float*)d_in[3];
    const float* l1j = (const float*)d_in[4],  *l1k = (const float*)d_in[5];
    const float* l1b = (const float*)d_in[6];
    const float* bn1g = (const float*)d_in[7], *bn1b = (const float*)d_in[8];
    const float* l2r = (const float*)d_in[9],  *l2i = (const float*)d_in[10];
    const float* l2j = (const float*)d_in[11], *l2k = (const float*)d_in[12];
    const float* l2b = (const float*)d_in[13];
    const float* bn2g = (const float*)d_in[14], *bn2b = (const float*)d_in[15];
    const float* l3r = (const float*)d_in[16], *l3i = (const float*)d_in[17];
    const float* l3j = (const float*)d_in[18], *l3k = (const float*)d_in[19];
    const float* l3b = (const float*)d_in[20];
    const float* bn3g = (const float*)d_in[21], *bn3b = (const float*)d_in[22];
    const float* fcr = (const float*)d_in[23], *fci = (const float*)d_in[24];
    const float* fcj = (const float*)d_in[25], *fck = (const float*)d_in[26];
    const float* fcb = (const float*)d_in[27];

    float* ws   = (float*)d_ws;
    float* outp = (float*)d_out;

    prep_kernel<<<512, 256, 0, stream>>>(l1r, l1i, l1j, l1k, l2r, l2i, l2j, l2k,
                                         l3r, l3i, l3j, l3k, fcr, fci, fcj, fck, ws);
    mean_kernel<<<51200, 256, 0, stream>>>(x, ws + WS_POOL);
    topk_kernel<<<256, 64, 0, stream>>>(ws + WS_POOL, w_eca, (int*)(ws + WS_IDX));
    conv1_kernel<<<1024, 256, 0, stream>>>(x, (const int*)(ws + WS_IDX), ws + WS_W1,
                                           l1b, ws + WS_OUT1, ws + WS_STATS);
    bnpool_kernel<16, 32, 4><<<4096, 256, 0, stream>>>(ws + WS_OUT1, ws + WS_P1,
        ws + WS_STATS, bn1g, bn1b, 1.0f / 1048576.0f);
    conv2_kernel<<<2048, 256, 0, stream>>>(ws + WS_P1, ws + WS_W2, l2b,
                                           ws + WS_OUT1, ws + WS_STATS + 8);
    bnpool_kernel<64, 16, 16><<<4096, 256, 0, stream>>>(ws + WS_OUT1, ws + WS_P1,
        ws + WS_STATS + 8, bn2g, bn2b, 1.0f / 1048576.0f);
    conv3_kernel<<<2048, 256, 0, stream>>>(ws + WS_P1, ws + WS_W3, l3b,
                                           ws + WS_OUT3, ws + WS_STATS + 16);
    bnpool_kernel<128, 8, 32><<<2048, 256, 0, stream>>>(ws + WS_OUT3, ws + WS_P3,
        ws + WS_STATS + 16, bn3g, bn3b, 1.0f / 524288.0f);
    fc_kernel<<<256, 256, 0, stream>>>(ws + WS_P3, ws + WS_WFC, fcb, outp);
}

// Round 4
// 433.411 us; speedup vs baseline: 2.2282x; 2.2282x over previous
//
#include <hip/hip_runtime.h>
#include <math.h>

// ---------------- workspace layout (float offsets) ----------------
#define WS_STATS 0         // 24 floats: [layer][S_r,S_i,S_j,S_k,Q_r,Q_i,Q_j,Q_k]
#define WS_W1    32        // 16*4*9   = 576      layout [s(4)][oc(16)][9]
#define WS_W2    640       // 64*16*9  = 9216     layout [ic(16)][k(9)][oc(64)]
#define WS_W3    9856      // 128*64*9 = 73728    layout [ic(64)][k(9)][oc(128)]
#define WS_WFC   83584     // 2048*16  = 32768
#define WS_POOL  116352    // 256*200  = 51200
#define WS_IDX   167552    // 256*3 ints
#define WS_OUT1  168448    // 256*16*32*32 = 4194304 (also OUT2)
#define WS_P1    4362752   // 256*16*16*16 = 1048576 (also P2)
#define WS_OUT3  5411328   // 256*128*8*8  = 2097152
#define WS_P3    7508480   // 256*128*4*4  = 524288

// Hamilton block table: T[a][b] -> (component, sign)
__device__ const int   d_TC[4][4] = {{0,1,2,3},{1,0,3,2},{2,3,0,1},{3,2,1,0}};
__device__ const float d_TS[4][4] = {{1.f,-1.f,-1.f,-1.f},{1.f,1.f,-1.f,1.f},
                                     {1.f,1.f,1.f,-1.f},{1.f,-1.f,1.f,1.f}};

// ---------------- prep: materialize W1/W2/W3/WFC, zero stats ----------------
__global__ __launch_bounds__(256) void prep_kernel(
    const float* l1r, const float* l1i, const float* l1j, const float* l1k,
    const float* l2r, const float* l2i, const float* l2j, const float* l2k,
    const float* l3r, const float* l3i, const float* l3j, const float* l3k,
    const float* fcr, const float* fci, const float* fcj, const float* fck,
    float* ws)
{
    int tid  = blockIdx.x * 256 + threadIdx.x;
    int nthr = gridDim.x * 256;
    if (tid < 24) ws[WS_STATS + tid] = 0.f;

    { // W1: [s(4)][oc(16)][9]
        const float* cp[4] = {l1r, l1i, l1j, l1k};
        for (int e = tid; e < 576; e += nthr) {
            int s = e / 144, rem = e % 144, oc = rem / 9, k = rem % 9;
            int p = oc >> 2, o = oc & 3;
            ws[WS_W1 + e] = d_TS[p][s] * cp[d_TC[p][s]][o * 9 + k];
        }
    }
    { // W2: [ic(16)][k(9)][oc(64)]
        const float* cp[4] = {l2r, l2i, l2j, l2k};
        for (int e = tid; e < 9216; e += nthr) {
            int oc = e & 63, k = (e >> 6) % 9, ic = e / 576;
            int p = oc >> 4, o = oc & 15, s = ic >> 2, ii = ic & 3;
            ws[WS_W2 + e] = d_TS[p][s] * cp[d_TC[p][s]][(o * 4 + ii) * 9 + k];
        }
    }
    { // W3: [ic(64)][k(9)][oc(128)]
        const float* cp[4] = {l3r, l3i, l3j, l3k};
        for (int e = tid; e < 73728; e += nthr) {
            int oc = e & 127, k = (e >> 7) % 9, ic = e / 1152;
            int p = oc >> 5, o = oc & 31, s = ic >> 4, ii = ic & 15;
            ws[WS_W3 + e] = d_TS[p][s] * cp[d_TC[p][s]][(o * 16 + ii) * 9 + k];
        }
    }
    { // WFC: 2048 x 16 from (512,4) components
        const float* cp[4] = {fcr, fci, fcj, fck};
        for (int e = tid; e < 32768; e += nthr) {
            int R = e >> 4, C = e & 15;
            int p = R >> 9, rr = R & 511, q = C >> 2, cc = C & 3;
            ws[WS_WFC + e] = d_TS[q][p] * cp[d_TC[q][p]][rr * 4 + cc];
        }
    }
}

// ---------------- global average pool over 32x32 per (b,c) ----------------
__global__ __launch_bounds__(256) void mean_kernel(const float* __restrict__ x,
                                                   float* __restrict__ pooled)
{
    int bc = blockIdx.x;                    // 256*200
    int t  = threadIdx.x;
    const float4* src = reinterpret_cast<const float4*>(x + (size_t)bc * 1024);
    float4 v = src[t];
    float s = v.x + v.y + v.z + v.w;
    #pragma unroll
    for (int off = 32; off; off >>= 1) s += __shfl_xor(s, off, 64);
    __shared__ float red[4];
    if ((t & 63) == 0) red[t >> 6] = s;
    __syncthreads();
    if (t == 0) pooled[bc] = (red[0] + red[1] + red[2] + red[3]) * (1.0f / 1024.0f);
}

// ---------------- top-3 channels of w*pooled (tie -> lowest idx) ----------------
__global__ __launch_bounds__(64) void topk_kernel(const float* __restrict__ pooled,
                                                  const float* __restrict__ w_eca,
                                                  int* __restrict__ idx3)
{
    int b = blockIdx.x, lane = threadIdx.x;
    float w = w_eca[0];
    float v[4]; int c[4];
    #pragma unroll
    for (int i = 0; i < 4; i++) {
        int ch = lane + 64 * i;
        c[i] = ch;
        v[i] = (ch < 200) ? w * pooled[b * 200 + ch] : -INFINITY;
    }
    for (int k = 0; k < 3; k++) {
        float bv = -INFINITY; int bi = 0x3fffffff;
        #pragma unroll
        for (int i = 0; i < 4; i++)
            if (v[i] > bv || (v[i] == bv && c[i] < bi)) { bv = v[i]; bi = c[i]; }
        for (int off = 32; off; off >>= 1) {
            float ov = __shfl_xor(bv, off, 64);
            int   oi = __shfl_xor(bi, off, 64);
            if (ov > bv || (ov == bv && oi < bi)) { bv = ov; bi = oi; }
        }
        if (lane == 0) idx3[b * 3 + k] = bi;
        #pragma unroll
        for (int i = 0; i < 4; i++) if (c[i] == bi) v[i] = -INFINITY;
    }
}

// ---------------- conv1: gather top3 -> 3x3 conv (4->16ch, 32x32) + stats ----------------
// grid 512 = 256 b * 2 oc-halves (8 oc each); thread = 4px; per-lane weight loads.
__global__ __launch_bounds__(256) void conv1_kernel(const float* __restrict__ x,
                                                    const int* __restrict__ idx3,
                                                    const float* __restrict__ W1,
                                                    const float* __restrict__ b1,
                                                    float* __restrict__ out1,
                                                    float* __restrict__ stats)
{
    __shared__ float smem[3][34][34];
    int b = blockIdx.x >> 1, half = blockIdx.x & 1;
    int t = threadIdx.x;
    float* l = &smem[0][0][0];
    for (int i = t; i < 3 * 34 * 34; i += 256) l[i] = 0.f;
    __syncthreads();
    #pragma unroll
    for (int s = 0; s < 3; s++) {
        const float* src = x + ((size_t)b * 200 + idx3[b * 3 + s]) * 1024;
        for (int i = t; i < 1024; i += 256)
            smem[s][(i >> 5) + 1][(i & 31) + 1] = src[i];
    }
    __syncthreads();

    int x0 = (t & 7) * 4, y = t >> 3;
    int oc0 = half * 8;
    float acc[8][4];
    #pragma unroll
    for (int o = 0; o < 8; o++) {
        float bb = b1[oc0 + o];
        acc[o][0] = bb; acc[o][1] = bb; acc[o][2] = bb; acc[o][3] = bb;
    }
    #pragma unroll
    for (int s = 0; s < 3; s++) {
        float n[3][6];
        #pragma unroll
        for (int dy = 0; dy < 3; dy++)
            #pragma unroll
            for (int dx = 0; dx < 6; dx++)
                n[dy][dx] = smem[s][y + dy][x0 + dx];
        #pragma unroll
        for (int o = 0; o < 8; o++) {
            const float* w = W1 + (s + 1) * 144 + (oc0 + o) * 9;
            float w0=w[0],w1=w[1],w2=w[2],w3=w[3],w4=w[4],w5=w[5],w6=w[6],w7=w[7],w8=w[8];
            #pragma unroll
            for (int p = 0; p < 4; p++) {
                float a = acc[o][p];
                a = fmaf(w0, n[0][p],   a); a = fmaf(w1, n[0][p+1], a); a = fmaf(w2, n[0][p+2], a);
                a = fmaf(w3, n[1][p],   a); a = fmaf(w4, n[1][p+1], a); a = fmaf(w5, n[1][p+2], a);
                a = fmaf(w6, n[2][p],   a); a = fmaf(w7, n[2][p+1], a); a = fmaf(w8, n[2][p+2], a);
                acc[o][p] = a;
            }
        }
    }
    float* outb = out1 + (size_t)b * 16384 + oc0 * 1024 + y * 32 + x0;
    float s2[2] = {0, 0}, q2[2] = {0, 0};
    #pragma unroll
    for (int o = 0; o < 8; o++) {
        float4 v = make_float4(acc[o][0], acc[o][1], acc[o][2], acc[o][3]);
        *reinterpret_cast<float4*>(outb + o * 1024) = v;
        int gl = o >> 2;
        s2[gl] += v.x + v.y + v.z + v.w;
        q2[gl] += v.x*v.x + v.y*v.y + v.z*v.z + v.w*v.w;
    }
    int lane = t & 63;
    #pragma unroll
    for (int gl = 0; gl < 2; gl++) {
        float sv = s2[gl], qv = q2[gl];
        #pragma unroll
        for (int off = 32; off; off >>= 1) { sv += __shfl_xor(sv, off, 64); qv += __shfl_xor(qv, off, 64); }
        if (lane == 0) { atomicAdd(&stats[half * 2 + gl], sv); atomicAdd(&stats[4 + half * 2 + gl], qv); }
    }
}

// ---------------- qbn + relu + 2x2 avg pool ----------------
template<int C, int H, int Cq>
__global__ __launch_bounds__(256) void bnpool_kernel(const float* __restrict__ in,
                                                     float* __restrict__ out,
                                                     const float* __restrict__ stats,
                                                     const float* __restrict__ gamma,
                                                     const float* __restrict__ beta,
                                                     float invN)
{
    constexpr int Ho = H / 2;
    int o = blockIdx.x * 256 + threadIdx.x;
    float mean[4]; float var = 0.f;
    #pragma unroll
    for (int g = 0; g < 4; g++) {
        float S = stats[g], Q = stats[4 + g];
        mean[g] = S * invN;
        var += Q - S * S * invN;
    }
    var *= invN;
    float inv = 1.0f / sqrtf(var + 1e-5f);

    int xq = o % Ho;
    int yq = (o / Ho) % Ho;
    int c  = (o / (Ho * Ho)) % C;
    int b  = o / (Ho * Ho * C);
    const float* base = in + ((size_t)((b * C + c) * H + 2 * yq)) * H + 2 * xq;
    float2 v01 = *reinterpret_cast<const float2*>(base);
    float2 v23 = *reinterpret_cast<const float2*>(base + H);
    int g = c / Cq, wv = c % Cq;
    float scale = gamma[wv] * inv;
    float sh = beta[c] - mean[g] * scale;
    float r0 = fmaxf(fmaf(v01.x, scale, sh), 0.f);
    float r1 = fmaxf(fmaf(v01.y, scale, sh), 0.f);
    float r2 = fmaxf(fmaf(v23.x, scale, sh), 0.f);
    float r3 = fmaxf(fmaf(v23.y, scale, sh), 0.f);
    out[o] = 0.25f * (r0 + r1 + r2 + r3);
}

// ---------------- conv2: 16->64 ch, 16x16; grid 1024 = 256 b * 4 ocg ----------------
// thread = (row r, oc-lane op): full 16-px row, coalesced [ic][k][oc] weight loads.
__global__ __launch_bounds__(256) void conv2_kernel(const float* __restrict__ p1,
                                                    const float* __restrict__ W2,
                                                    const float* __restrict__ b2,
                                                    float* __restrict__ out2,
                                                    float* __restrict__ stats)
{
    __shared__ float smem[16][18][20];   // padded stride 20 (80B, 16B-aligned rows)
    int b = blockIdx.x >> 2, ocg = blockIdx.x & 3;
    int t = threadIdx.x;
    float* l = &smem[0][0][0];
    for (int i = t; i < 16 * 18 * 20; i += 256) l[i] = 0.f;
    __syncthreads();
    const float* src = p1 + (size_t)b * 4096;
    for (int i = t; i < 4096; i += 256) {
        int ic = i >> 8, rem = i & 255;
        smem[ic][(rem >> 4) + 1][(rem & 15) + 1] = src[i];
    }
    __syncthreads();

    int r = t >> 4, op = t & 15;
    int oc = ocg * 16 + op;
    float acc[16];
    float bb = b2[oc];
    #pragma unroll
    for (int px = 0; px < 16; px++) acc[px] = bb;

    const float* Wp = W2 + oc;
    for (int ic = 0; ic < 16; ic++) {
        float w[9];
        #pragma unroll
        for (int k = 0; k < 9; k++) w[k] = Wp[ic * 576 + k * 64];
        // left 8 px: smem cols 0..9
        {
            float n[3][10];
            #pragma unroll
            for (int dy = 0; dy < 3; dy++) {
                const float* rp = &smem[ic][r + dy][0];
                float4 a4 = *reinterpret_cast<const float4*>(rp);
                float4 c4 = *reinterpret_cast<const float4*>(rp + 4);
                float2 e2 = *reinterpret_cast<const float2*>(rp + 8);
                n[dy][0]=a4.x; n[dy][1]=a4.y; n[dy][2]=a4.z; n[dy][3]=a4.w;
                n[dy][4]=c4.x; n[dy][5]=c4.y; n[dy][6]=c4.z; n[dy][7]=c4.w;
                n[dy][8]=e2.x; n[dy][9]=e2.y;
            }
            #pragma unroll
            for (int px = 0; px < 8; px++) {
                float a = acc[px];
                #pragma unroll
                for (int dy = 0; dy < 3; dy++) {
                    a = fmaf(w[dy*3+0], n[dy][px],   a);
                    a = fmaf(w[dy*3+1], n[dy][px+1], a);
                    a = fmaf(w[dy*3+2], n[dy][px+2], a);
                }
                acc[px] = a;
            }
        }
        // right 8 px: smem cols 8..17
        {
            float n[3][10];
            #pragma unroll
            for (int dy = 0; dy < 3; dy++) {
                const float* rp = &smem[ic][r + dy][8];
                float4 a4 = *reinterpret_cast<const float4*>(rp);
                float4 c4 = *reinterpret_cast<const float4*>(rp + 4);
                float2 e2 = *reinterpret_cast<const float2*>(rp + 8);
                n[dy][0]=a4.x; n[dy][1]=a4.y; n[dy][2]=a4.z; n[dy][3]=a4.w;
                n[dy][4]=c4.x; n[dy][5]=c4.y; n[dy][6]=c4.z; n[dy][7]=c4.w;
                n[dy][8]=e2.x; n[dy][9]=e2.y;
            }
            #pragma unroll
            for (int px = 0; px < 8; px++) {
                float a = acc[8 + px];
                #pragma unroll
                for (int dy = 0; dy < 3; dy++) {
                    a = fmaf(w[dy*3+0], n[dy][px],   a);
                    a = fmaf(w[dy*3+1], n[dy][px+1], a);
                    a = fmaf(w[dy*3+2], n[dy][px+2], a);
                }
                acc[8 + px] = a;
            }
        }
    }
    float* outb = out2 + (size_t)b * 16384 + oc * 256 + r * 16;
    float sv = 0.f, qv = 0.f;
    #pragma unroll
    for (int q4 = 0; q4 < 4; q4++) {
        float4 v = make_float4(acc[q4*4], acc[q4*4+1], acc[q4*4+2], acc[q4*4+3]);
        *reinterpret_cast<float4*>(outb + q4 * 4) = v;
        sv += v.x + v.y + v.z + v.w;
        qv += v.x*v.x + v.y*v.y + v.z*v.z + v.w*v.w;
    }
    int lane = t & 63;
    #pragma unroll
    for (int off = 32; off; off >>= 1) { sv += __shfl_xor(sv, off, 64); qv += __shfl_xor(qv, off, 64); }
    if (lane == 0) { atomicAdd(&stats[ocg], sv); atomicAdd(&stats[4 + ocg], qv); }
}

// ---------------- conv3: 64->128 ch, 8x8; grid 1024 = 256 b * 4 ocg ----------------
// thread = (row r, oc-lane op of 32): full 8-px row; coalesced [ic][k][oc] weights.
__global__ __launch_bounds__(256) void conv3_kernel(const float* __restrict__ p2,
                                                    const float* __restrict__ W3,
                                                    const float* __restrict__ b3,
                                                    float* __restrict__ out3,
                                                    float* __restrict__ stats)
{
    __shared__ float smem[64][10][12];   // padded stride 12 (48B rows), 30.7 KB
    int b = blockIdx.x >> 2, ocg = blockIdx.x & 3;
    int t = threadIdx.x;
    float* l = &smem[0][0][0];
    for (int i = t; i < 64 * 10 * 12; i += 256) l[i] = 0.f;
    __syncthreads();
    const float* src = p2 + (size_t)b * 4096;
    for (int i = t; i < 4096; i += 256) {
        int ic = i >> 6, px = i & 63;
        smem[ic][(px >> 3) + 1][(px & 7) + 1] = src[i];
    }
    __syncthreads();

    int r = t >> 5, op = t & 31;
    int oc = ocg * 32 + op;
    float acc[8];
    float bb = b3[oc];
    #pragma unroll
    for (int px = 0; px < 8; px++) acc[px] = bb;

    const float* Wp = W3 + oc;
    for (int ic = 0; ic < 64; ic++) {
        float w[9];
        #pragma unroll
        for (int k = 0; k < 9; k++) w[k] = Wp[ic * 1152 + k * 128];
        float n[3][10];
        #pragma unroll
        for (int dy = 0; dy < 3; dy++) {
            const float* rp = &smem[ic][r + dy][0];
            float4 a4 = *reinterpret_cast<const float4*>(rp);
            float4 c4 = *reinterpret_cast<const float4*>(rp + 4);
            float2 e2 = *reinterpret_cast<const float2*>(rp + 8);
            n[dy][0]=a4.x; n[dy][1]=a4.y; n[dy][2]=a4.z; n[dy][3]=a4.w;
            n[dy][4]=c4.x; n[dy][5]=c4.y; n[dy][6]=c4.z; n[dy][7]=c4.w;
            n[dy][8]=e2.x; n[dy][9]=e2.y;
        }
        #pragma unroll
        for (int px = 0; px < 8; px++) {
            float a = acc[px];
            #pragma unroll
            for (int dy = 0; dy < 3; dy++) {
                a = fmaf(w[dy*3+0], n[dy][px],   a);
                a = fmaf(w[dy*3+1], n[dy][px+1], a);
                a = fmaf(w[dy*3+2], n[dy][px+2], a);
            }
            acc[px] = a;
        }
    }
    float* outb = out3 + (size_t)b * 8192 + oc * 64 + r * 8;
    float4 v0 = make_float4(acc[0], acc[1], acc[2], acc[3]);
    float4 v1 = make_float4(acc[4], acc[5], acc[6], acc[7]);
    *reinterpret_cast<float4*>(outb)     = v0;
    *reinterpret_cast<float4*>(outb + 4) = v1;
    float sv = v0.x+v0.y+v0.z+v0.w + v1.x+v1.y+v1.z+v1.w;
    float qv = v0.x*v0.x+v0.y*v0.y+v0.z*v0.z+v0.w*v0.w
             + v1.x*v1.x+v1.y*v1.y+v1.z*v1.z+v1.w*v1.w;
    int lane = t & 63;
    #pragma unroll
    for (int off = 32; off; off >>= 1) { sv += __shfl_xor(sv, off, 64); qv += __shfl_xor(qv, off, 64); }
    if (lane == 0) { atomicAdd(&stats[ocg], sv); atomicAdd(&stats[4 + ocg], qv); }
}

// ---------------- fc: [256,2048] @ [2048,16] + b ----------------
__global__ __launch_bounds__(256) void fc_kernel(const float* __restrict__ p3,
                                                 const float* __restrict__ WFC,
                                                 const float* __restrict__ fcb,
                                                 float* __restrict__ out)
{
    int b = blockIdx.x, t = threadIdx.x;
    int col = t & 15, fr = t >> 4;
    const float* pb = p3 + (size_t)b * 2048;
    float s = 0.f;
    for (int i = 0; i < 128; i++) {
        int f = i * 16 + fr;
        s = fmaf(pb[f], WFC[f * 16 + col], s);
    }
    __shared__ float red[256];
    red[t] = s;
    __syncthreads();
    for (int st = 128; st >= 16; st >>= 1) {
        if (t < st) red[t] += red[t + st];
        __syncthreads();
    }
    if (t < 16) out[b * 16 + t] = red[t] + fcb[t];
}

// ---------------- launch ----------------
extern "C" void kernel_launch(void* const* d_in, const int* in_sizes, int n_in,
                              void* d_out, int out_size, void* d_ws, size_t ws_size,
                              hipStream_t stream)
{
    (void)in_sizes; (void)n_in; (void)out_size; (void)ws_size;
    const float* x     = (const float*)d_in[0];
    const float* w_eca = (const float*)d_in[1];
    const float* l1r = (const float*)d_in[2],  *l1i = (const float*)d_in[3];
    const float* l1j = (const float*)d_in[4],  *l1k = (const float*)d_in[5];
    const float* l1b = (const float*)d_in[6];
    const float* bn1g = (const float*)d_in[7], *bn1b = (const float*)d_in[8];
    const float* l2r = (const float*)d_in[9],  *l2i = (const float*)d_in[10];
    const float* l2j = (const float*)d_in[11], *l2k = (const float*)d_in[12];
    const float* l2b = (const float*)d_in[13];
    const float* bn2g = (const float*)d_in[14], *bn2b = (const float*)d_in[15];
    const float* l3r = (const float*)d_in[16], *l3i = (const float*)d_in[17];
    const float* l3j = (const float*)d_in[18], *l3k = (const float*)d_in[19];
    const float* l3b = (const float*)d_in[20];
    const float* bn3g = (const float*)d_in[21], *bn3b = (const float*)d_in[22];
    const float* fcr = (const float*)d_in[23], *fci = (const float*)d_in[24];
    const float* fcj = (const float*)d_in[25], *fck = (const float*)d_in[26];
    const float* fcb = (const float*)d_in[27];

    float* ws   = (float*)d_ws;
    float* outp = (float*)d_out;

    prep_kernel<<<512, 256, 0, stream>>>(l1r, l1i, l1j, l1k, l2r, l2i, l2j, l2k,
                                         l3r, l3i, l3j, l3k, fcr, fci, fcj, fck, ws);
    mean_kernel<<<51200, 256, 0, stream>>>(x, ws + WS_POOL);
    topk_kernel<<<256, 64, 0, stream>>>(ws + WS_POOL, w_eca, (int*)(ws + WS_IDX));
    conv1_kernel<<<512, 256, 0, stream>>>(x, (const int*)(ws + WS_IDX), ws + WS_W1,
                                          l1b, ws + WS_OUT1, ws + WS_STATS);
    bnpool_kernel<16, 32, 4><<<4096, 256, 0, stream>>>(ws + WS_OUT1, ws + WS_P1,
        ws + WS_STATS, bn1g, bn1b, 1.0f / 1048576.0f);
    conv2_kernel<<<1024, 256, 0, stream>>>(ws + WS_P1, ws + WS_W2, l2b,
                                           ws + WS_OUT1, ws + WS_STATS + 8);
    bnpool_kernel<64, 16, 16><<<4096, 256, 0, stream>>>(ws + WS_OUT1, ws + WS_P1,
        ws + WS_STATS + 8, bn2g, bn2b, 1.0f / 1048576.0f);
    conv3_kernel<<<1024, 256, 0, stream>>>(ws + WS_P1, ws + WS_W3, l3b,
                                           ws + WS_OUT3, ws + WS_STATS + 16);
    bnpool_kernel<128, 8, 32><<<2048, 256, 0, stream>>>(ws + WS_OUT3, ws + WS_P3,
        ws + WS_STATS + 16, bn3g, bn3b, 1.0f / 524288.0f);
    fc_kernel<<<256, 256, 0, stream>>>(ws + WS_P3, ws + WS_WFC, fcb, outp);
}

// Round 5
// 190.877 us; speedup vs baseline: 5.0594x; 2.2706x over previous
//
#include <hip/hip_runtime.h>
#include <math.h>

// ---------------- workspace layout (float offsets) ----------------
#define WS_STATS 0         // 24 floats: [layer][S_r,S_i,S_j,S_k,Q_r,Q_i,Q_j,Q_k]
#define WS_W1    32        // 16*4*9   = 576      layout [s(4)][k(9)][oc(16)]
#define WS_W2    640       // 64*16*9  = 9216     layout [ic(16)][k(9)][oc(64)]
#define WS_W3    9856      // 128*64*9 = 73728    layout [ic(64)][k(9)][oc(128)]
#define WS_WFC   83584     // 2048*16  = 32768
#define WS_POOL  116352    // 256*200  = 51200
#define WS_IDX   167552    // 256*3 ints
#define WS_OUT1  168448    // 256*16*32*32 = 4194304 (also OUT2)
#define WS_P1    4362752   // 256*16*16*16 = 1048576 (also P2)
#define WS_OUT3  5411328   // 256*128*8*8  = 2097152
#define WS_P3    7508480   // 256*128*4*4  = 524288

// Hamilton block table: T[a][b] -> (component, sign)
__device__ const int   d_TC[4][4] = {{0,1,2,3},{1,0,3,2},{2,3,0,1},{3,2,1,0}};
__device__ const float d_TS[4][4] = {{1.f,-1.f,-1.f,-1.f},{1.f,1.f,-1.f,1.f},
                                     {1.f,1.f,1.f,-1.f},{1.f,-1.f,1.f,1.f}};

// ---------------- prep: materialize W1/W2/W3/WFC, zero stats ----------------
__global__ __launch_bounds__(256) void prep_kernel(
    const float* l1r, const float* l1i, const float* l1j, const float* l1k,
    const float* l2r, const float* l2i, const float* l2j, const float* l2k,
    const float* l3r, const float* l3i, const float* l3j, const float* l3k,
    const float* fcr, const float* fci, const float* fcj, const float* fck,
    float* ws)
{
    int tid  = blockIdx.x * 256 + threadIdx.x;
    int nthr = gridDim.x * 256;
    if (tid < 24) ws[WS_STATS + tid] = 0.f;

    { // W1: [s(4)][k(9)][oc(16)]
        const float* cp[4] = {l1r, l1i, l1j, l1k};
        for (int e = tid; e < 576; e += nthr) {
            int s = e / 144, rem = e % 144, k = rem / 16, oc = rem % 16;
            int p = oc >> 2, o = oc & 3;
            ws[WS_W1 + e] = d_TS[p][s] * cp[d_TC[p][s]][o * 9 + k];
        }
    }
    { // W2: [ic(16)][k(9)][oc(64)]
        const float* cp[4] = {l2r, l2i, l2j, l2k};
        for (int e = tid; e < 9216; e += nthr) {
            int oc = e & 63, k = (e >> 6) % 9, ic = e / 576;
            int p = oc >> 4, o = oc & 15, s = ic >> 2, ii = ic & 3;
            ws[WS_W2 + e] = d_TS[p][s] * cp[d_TC[p][s]][(o * 4 + ii) * 9 + k];
        }
    }
    { // W3: [ic(64)][k(9)][oc(128)]
        const float* cp[4] = {l3r, l3i, l3j, l3k};
        for (int e = tid; e < 73728; e += nthr) {
            int oc = e & 127, k = (e >> 7) % 9, ic = e / 1152;
            int p = oc >> 5, o = oc & 31, s = ic >> 4, ii = ic & 15;
            ws[WS_W3 + e] = d_TS[p][s] * cp[d_TC[p][s]][(o * 16 + ii) * 9 + k];
        }
    }
    { // WFC: 2048 x 16 from (512,4) components
        const float* cp[4] = {fcr, fci, fcj, fck};
        for (int e = tid; e < 32768; e += nthr) {
            int R = e >> 4, C = e & 15;
            int p = R >> 9, rr = R & 511, q = C >> 2, cc = C & 3;
            ws[WS_WFC + e] = d_TS[q][p] * cp[d_TC[q][p]][rr * 4 + cc];
        }
    }
}

// ---------------- global average pool over 32x32 per (b,c) ----------------
__global__ __launch_bounds__(256) void mean_kernel(const float* __restrict__ x,
                                                   float* __restrict__ pooled)
{
    int bc = blockIdx.x;                    // 256*200
    int t  = threadIdx.x;
    const float4* src = reinterpret_cast<const float4*>(x + (size_t)bc * 1024);
    float4 v = src[t];
    float s = v.x + v.y + v.z + v.w;
    #pragma unroll
    for (int off = 32; off; off >>= 1) s += __shfl_xor(s, off, 64);
    __shared__ float red[4];
    if ((t & 63) == 0) red[t >> 6] = s;
    __syncthreads();
    if (t == 0) pooled[bc] = (red[0] + red[1] + red[2] + red[3]) * (1.0f / 1024.0f);
}

// ---------------- top-3 channels of w*pooled (tie -> lowest idx) ----------------
__global__ __launch_bounds__(64) void topk_kernel(const float* __restrict__ pooled,
                                                  const float* __restrict__ w_eca,
                                                  int* __restrict__ idx3)
{
    int b = blockIdx.x, lane = threadIdx.x;
    float w = w_eca[0];
    float v[4]; int c[4];
    #pragma unroll
    for (int i = 0; i < 4; i++) {
        int ch = lane + 64 * i;
        c[i] = ch;
        v[i] = (ch < 200) ? w * pooled[b * 200 + ch] : -INFINITY;
    }
    for (int k = 0; k < 3; k++) {
        float bv = -INFINITY; int bi = 0x3fffffff;
        #pragma unroll
        for (int i = 0; i < 4; i++)
            if (v[i] > bv || (v[i] == bv && c[i] < bi)) { bv = v[i]; bi = c[i]; }
        for (int off = 32; off; off >>= 1) {
            float ov = __shfl_xor(bv, off, 64);
            int   oi = __shfl_xor(bi, off, 64);
            if (ov > bv || (ov == bv && oi < bi)) { bv = ov; bi = oi; }
        }
        if (lane == 0) idx3[b * 3 + k] = bi;
        #pragma unroll
        for (int i = 0; i < 4; i++) if (c[i] == bi) v[i] = -INFINITY;
    }
}

// ---------------- conv1: 4->16 ch, 32x32; grid 2048 = 256 b * 8 rowgroups(4) ----
// thread = (oc 16, row 4, colgroup 4 of 8 px); LDS reads 16-lane broadcast.
__global__ __launch_bounds__(256) void conv1_kernel(const float* __restrict__ x,
                                                    const int* __restrict__ idx3,
                                                    const float* __restrict__ W1,
                                                    const float* __restrict__ b1,
                                                    float* __restrict__ out1,
                                                    float* __restrict__ stats)
{
    __shared__ float smem[3][6][36];   // rows rg*4-1..+4, cols -1..34
    __shared__ float rs[8];
    int b = blockIdx.x >> 3, rg = blockIdx.x & 7;
    int t = threadIdx.x;
    if (t < 8) rs[t] = 0.f;
    for (int i = t; i < 648; i += 256) {
        int s = i / 216, rem = i % 216, r = rem / 36, c = rem % 36;
        int gr = rg * 4 - 1 + r, gc = c - 1;
        float v = 0.f;
        if (gr >= 0 && gr < 32 && gc >= 0 && gc < 32)
            v = x[((size_t)b * 200 + idx3[b * 3 + s]) * 1024 + gr * 32 + gc];
        smem[s][r][c] = v;
    }
    __syncthreads();

    int oc = t & 15, rp = (t >> 4) & 3, ch = t >> 6;
    float bb = b1[oc];
    float acc[8];
    #pragma unroll
    for (int px = 0; px < 8; px++) acc[px] = bb;

    #pragma unroll
    for (int s = 0; s < 3; s++) {
        float w[9];
        #pragma unroll
        for (int k = 0; k < 9; k++) w[k] = W1[((s + 1) * 9 + k) * 16 + oc];
        float rowv[3][12];
        #pragma unroll
        for (int dy = 0; dy < 3; dy++) {
            const float* rb = &smem[s][rp + dy][ch * 8];
            float4 a = *reinterpret_cast<const float4*>(rb);
            float4 bq = *reinterpret_cast<const float4*>(rb + 4);
            float4 cq = *reinterpret_cast<const float4*>(rb + 8);
            rowv[dy][0]=a.x;  rowv[dy][1]=a.y;  rowv[dy][2]=a.z;  rowv[dy][3]=a.w;
            rowv[dy][4]=bq.x; rowv[dy][5]=bq.y; rowv[dy][6]=bq.z; rowv[dy][7]=bq.w;
            rowv[dy][8]=cq.x; rowv[dy][9]=cq.y; rowv[dy][10]=cq.z; rowv[dy][11]=cq.w;
        }
        #pragma unroll
        for (int dy = 0; dy < 3; dy++)
            #pragma unroll
            for (int px = 0; px < 8; px++) {
                float a = acc[px];
                a = fmaf(w[dy*3+0], rowv[dy][px],   a);
                a = fmaf(w[dy*3+1], rowv[dy][px+1], a);
                a = fmaf(w[dy*3+2], rowv[dy][px+2], a);
                acc[px] = a;
            }
    }
    int row = rg * 4 + rp;
    float* outb = out1 + ((size_t)b * 16 + oc) * 1024 + row * 32 + ch * 8;
    *reinterpret_cast<float4*>(outb)     = make_float4(acc[0], acc[1], acc[2], acc[3]);
    *reinterpret_cast<float4*>(outb + 4) = make_float4(acc[4], acc[5], acc[6], acc[7]);
    float sv = 0.f, qv = 0.f;
    #pragma unroll
    for (int px = 0; px < 8; px++) { sv += acc[px]; qv += acc[px] * acc[px]; }
    int g = oc >> 2;
    atomicAdd(&rs[g], sv); atomicAdd(&rs[4 + g], qv);
    __syncthreads();
    if (t < 8) atomicAdd(&stats[t], rs[t]);
}

// ---------------- qbn + relu + 2x2 avg pool ----------------
template<int C, int H, int Cq>
__global__ __launch_bounds__(256) void bnpool_kernel(const float* __restrict__ in,
                                                     float* __restrict__ out,
                                                     const float* __restrict__ stats,
                                                     const float* __restrict__ gamma,
                                                     const float* __restrict__ beta,
                                                     float invN)
{
    constexpr int Ho = H / 2;
    int o = blockIdx.x * 256 + threadIdx.x;
    float mean[4]; float var = 0.f;
    #pragma unroll
    for (int g = 0; g < 4; g++) {
        float S = stats[g], Q = stats[4 + g];
        mean[g] = S * invN;
        var += Q - S * S * invN;
    }
    var *= invN;
    float inv = 1.0f / sqrtf(var + 1e-5f);

    int xq = o % Ho;
    int yq = (o / Ho) % Ho;
    int c  = (o / (Ho * Ho)) % C;
    int b  = o / (Ho * Ho * C);
    const float* base = in + ((size_t)((b * C + c) * H + 2 * yq)) * H + 2 * xq;
    float2 v01 = *reinterpret_cast<const float2*>(base);
    float2 v23 = *reinterpret_cast<const float2*>(base + H);
    int g = c / Cq, wv = c % Cq;
    float scale = gamma[wv] * inv;
    float sh = beta[c] - mean[g] * scale;
    float r0 = fmaxf(fmaf(v01.x, scale, sh), 0.f);
    float r1 = fmaxf(fmaf(v01.y, scale, sh), 0.f);
    float r2 = fmaxf(fmaf(v23.x, scale, sh), 0.f);
    float r3 = fmaxf(fmaf(v23.y, scale, sh), 0.f);
    out[o] = 0.25f * (r0 + r1 + r2 + r3);
}

// ---------------- conv2: 16->64 ch, 16x16; grid 2048 = 256 b * 8 rowpairs ----
// thread = (oc 64-lane, rowpair-row 2, colhalf 2); LDS reads wave-broadcast.
__global__ __launch_bounds__(256) void conv2_kernel(const float* __restrict__ p1,
                                                    const float* __restrict__ W2,
                                                    const float* __restrict__ b2,
                                                    float* __restrict__ out2,
                                                    float* __restrict__ stats)
{
    __shared__ float smem[16][4][20];   // rows rq*2-1..+2, cols -1..18
    __shared__ float rs[8];
    int b = blockIdx.x >> 3, rq = blockIdx.x & 7;
    int t = threadIdx.x;
    if (t < 8) rs[t] = 0.f;
    for (int i = t; i < 1280; i += 256) {
        int ic = i / 80, rem = i % 80, r = rem / 20, c = rem % 20;
        int gr = rq * 2 - 1 + r, gc = c - 1;
        float v = 0.f;
        if (gr >= 0 && gr < 16 && gc >= 0 && gc < 16)
            v = p1[((size_t)b * 16 + ic) * 256 + gr * 16 + gc];
        smem[ic][r][c] = v;
    }
    __syncthreads();

    int oc = t & 63, rp = (t >> 6) & 1, ch = t >> 7;
    float bb = b2[oc];
    float acc[8];
    #pragma unroll
    for (int px = 0; px < 8; px++) acc[px] = bb;

    const float* Wp = W2 + oc;
    for (int ic = 0; ic < 16; ic++) {
        float w[9];
        #pragma unroll
        for (int k = 0; k < 9; k++) w[k] = Wp[ic * 576 + k * 64];
        float rowv[3][12];
        #pragma unroll
        for (int dy = 0; dy < 3; dy++) {
            const float* rb = &smem[ic][rp + dy][ch * 8];
            float4 a = *reinterpret_cast<const float4*>(rb);
            float4 bq = *reinterpret_cast<const float4*>(rb + 4);
            float4 cq = *reinterpret_cast<const float4*>(rb + 8);
            rowv[dy][0]=a.x;  rowv[dy][1]=a.y;  rowv[dy][2]=a.z;  rowv[dy][3]=a.w;
            rowv[dy][4]=bq.x; rowv[dy][5]=bq.y; rowv[dy][6]=bq.z; rowv[dy][7]=bq.w;
            rowv[dy][8]=cq.x; rowv[dy][9]=cq.y; rowv[dy][10]=cq.z; rowv[dy][11]=cq.w;
        }
        #pragma unroll
        for (int dy = 0; dy < 3; dy++)
            #pragma unroll
            for (int px = 0; px < 8; px++) {
                float a = acc[px];
                a = fmaf(w[dy*3+0], rowv[dy][px],   a);
                a = fmaf(w[dy*3+1], rowv[dy][px+1], a);
                a = fmaf(w[dy*3+2], rowv[dy][px+2], a);
                acc[px] = a;
            }
    }
    int row = rq * 2 + rp;
    float* outb = out2 + ((size_t)b * 64 + oc) * 256 + row * 16 + ch * 8;
    *reinterpret_cast<float4*>(outb)     = make_float4(acc[0], acc[1], acc[2], acc[3]);
    *reinterpret_cast<float4*>(outb + 4) = make_float4(acc[4], acc[5], acc[6], acc[7]);
    float sv = 0.f, qv = 0.f;
    #pragma unroll
    for (int px = 0; px < 8; px++) { sv += acc[px]; qv += acc[px] * acc[px]; }
    int g = oc >> 4;
    atomicAdd(&rs[g], sv); atomicAdd(&rs[4 + g], qv);
    __syncthreads();
    if (t < 8) atomicAdd(&stats[t], rs[t]);
}

// ---------------- conv3: 64->128 ch, 8x8; grid 1024 = 256 b * 4 rowpairs ----
// thread = (oc 128, row 2); coalesced prefetched weights; broadcast LDS input.
__global__ __launch_bounds__(256) void conv3_kernel(const float* __restrict__ p2,
                                                    const float* __restrict__ W3,
                                                    const float* __restrict__ b3,
                                                    float* __restrict__ out3,
                                                    float* __restrict__ stats)
{
    __shared__ float smem[64][4][12];   // rows rh*2-1..+2, cols -1..10
    __shared__ float rs[8];
    int b = blockIdx.x >> 2, rh = blockIdx.x & 3;
    int t = threadIdx.x;
    if (t < 8) rs[t] = 0.f;
    for (int i = t; i < 3072; i += 256) {
        int ic = i / 48, rem = i % 48, r = rem / 12, c = rem % 12;
        int gr = rh * 2 - 1 + r, gc = c - 1;
        float v = 0.f;
        if (gr >= 0 && gr < 8 && gc >= 0 && gc < 8)
            v = p2[((size_t)b * 64 + ic) * 64 + gr * 8 + gc];
        smem[ic][r][c] = v;
    }
    __syncthreads();

    int oc = t & 127, rp = t >> 7;
    float bb = b3[oc];
    float acc[8];
    #pragma unroll
    for (int px = 0; px < 8; px++) acc[px] = bb;

    const float* Wp = W3 + oc;
    float w[9], wn[9];
    #pragma unroll
    for (int k = 0; k < 9; k++) w[k] = Wp[k * 128];
    for (int ic = 0; ic < 64; ic++) {
        if (ic < 63) {
            #pragma unroll
            for (int k = 0; k < 9; k++) wn[k] = Wp[(ic + 1) * 1152 + k * 128];
        }
        float rowv[3][12];
        #pragma unroll
        for (int dy = 0; dy < 3; dy++) {
            const float* rb = &smem[ic][rp + dy][0];
            float4 a = *reinterpret_cast<const float4*>(rb);
            float4 bq = *reinterpret_cast<const float4*>(rb + 4);
            float4 cq = *reinterpret_cast<const float4*>(rb + 8);
            rowv[dy][0]=a.x;  rowv[dy][1]=a.y;  rowv[dy][2]=a.z;  rowv[dy][3]=a.w;
            rowv[dy][4]=bq.x; rowv[dy][5]=bq.y; rowv[dy][6]=bq.z; rowv[dy][7]=bq.w;
            rowv[dy][8]=cq.x; rowv[dy][9]=cq.y; rowv[dy][10]=cq.z; rowv[dy][11]=cq.w;
        }
        #pragma unroll
        for (int dy = 0; dy < 3; dy++)
            #pragma unroll
            for (int px = 0; px < 8; px++) {
                float a = acc[px];
                a = fmaf(w[dy*3+0], rowv[dy][px],   a);
                a = fmaf(w[dy*3+1], rowv[dy][px+1], a);
                a = fmaf(w[dy*3+2], rowv[dy][px+2], a);
                acc[px] = a;
            }
        if (ic < 63) {
            #pragma unroll
            for (int k = 0; k < 9; k++) w[k] = wn[k];
        }
    }
    int row = rh * 2 + rp;
    float* outb = out3 + ((size_t)b * 128 + oc) * 64 + row * 8;
    *reinterpret_cast<float4*>(outb)     = make_float4(acc[0], acc[1], acc[2], acc[3]);
    *reinterpret_cast<float4*>(outb + 4) = make_float4(acc[4], acc[5], acc[6], acc[7]);
    float sv = 0.f, qv = 0.f;
    #pragma unroll
    for (int px = 0; px < 8; px++) { sv += acc[px]; qv += acc[px] * acc[px]; }
    int g = oc >> 5;
    atomicAdd(&rs[g], sv); atomicAdd(&rs[4 + g], qv);
    __syncthreads();
    if (t < 8) atomicAdd(&stats[t], rs[t]);
}

// ---------------- fc: [256,2048] @ [2048,16] + b ----------------
__global__ __launch_bounds__(256) void fc_kernel(const float* __restrict__ p3,
                                                 const float* __restrict__ WFC,
                                                 const float* __restrict__ fcb,
                                                 float* __restrict__ out)
{
    int b = blockIdx.x, t = threadIdx.x;
    int col = t & 15, fr = t >> 4;
    const float* pb = p3 + (size_t)b * 2048;
    float s = 0.f;
    for (int i = 0; i < 128; i++) {
        int f = i * 16 + fr;
        s = fmaf(pb[f], WFC[f * 16 + col], s);
    }
    __shared__ float red[256];
    red[t] = s;
    __syncthreads();
    for (int st = 128; st >= 16; st >>= 1) {
        if (t < st) red[t] += red[t + st];
        __syncthreads();
    }
    if (t < 16) out[b * 16 + t] = red[t] + fcb[t];
}

// ---------------- launch ----------------
extern "C" void kernel_launch(void* const* d_in, const int* in_sizes, int n_in,
                              void* d_out, int out_size, void* d_ws, size_t ws_size,
                              hipStream_t stream)
{
    (void)in_sizes; (void)n_in; (void)out_size; (void)ws_size;
    const float* x     = (const float*)d_in[0];
    const float* w_eca = (const float*)d_in[1];
    const float* l1r = (const float*)d_in[2],  *l1i = (const float*)d_in[3];
    const float* l1j = (const float*)d_in[4],  *l1k = (const float*)d_in[5];
    const float* l1b = (const float*)d_in[6];
    const float* bn1g = (const float*)d_in[7], *bn1b = (const float*)d_in[8];
    const float* l2r = (const float*)d_in[9],  *l2i = (const float*)d_in[10];
    const float* l2j = (const float*)d_in[11], *l2k = (const float*)d_in[12];
    const float* l2b = (const float*)d_in[13];
    const float* bn2g = (const float*)d_in[14], *bn2b = (const float*)d_in[15];
    const float* l3r = (const float*)d_in[16], *l3i = (const float*)d_in[17];
    const float* l3j = (const float*)d_in[18], *l3k = (const float*)d_in[19];
    const float* l3b = (const float*)d_in[20];
    const float* bn3g = (const float*)d_in[21], *bn3b = (const float*)d_in[22];
    const float* fcr = (const float*)d_in[23], *fci = (const float*)d_in[24];
    const float* fcj = (const float*)d_in[25], *fck = (const float*)d_in[26];
    const float* fcb = (const float*)d_in[27];

    float* ws   = (float*)d_ws;
    float* outp = (float*)d_out;

    prep_kernel<<<512, 256, 0, stream>>>(l1r, l1i, l1j, l1k, l2r, l2i, l2j, l2k,
                                         l3r, l3i, l3j, l3k, fcr, fci, fcj, fck, ws);
    mean_kernel<<<51200, 256, 0, stream>>>(x, ws + WS_POOL);
    topk_kernel<<<256, 64, 0, stream>>>(ws + WS_POOL, w_eca, (int*)(ws + WS_IDX));
    conv1_kernel<<<2048, 256, 0, stream>>>(x, (const int*)(ws + WS_IDX), ws + WS_W1,
                                           l1b, ws + WS_OUT1, ws + WS_STATS);
    bnpool_kernel<16, 32, 4><<<4096, 256, 0, stream>>>(ws + WS_OUT1, ws + WS_P1,
        ws + WS_STATS, bn1g, bn1b, 1.0f / 1048576.0f);
    conv2_kernel<<<2048, 256, 0, stream>>>(ws + WS_P1, ws + WS_W2, l2b,
                                           ws + WS_OUT1, ws + WS_STATS + 8);
    bnpool_kernel<64, 16, 16><<<4096, 256, 0, stream>>>(ws + WS_OUT1, ws + WS_P1,
        ws + WS_STATS + 8, bn2g, bn2b, 1.0f / 1048576.0f);
    conv3_kernel<<<1024, 256, 0, stream>>>(ws + WS_P1, ws + WS_W3, l3b,
                                           ws + WS_OUT3, ws + WS_STATS + 16);
    bnpool_kernel<128, 8, 32><<<2048, 256, 0, stream>>>(ws + WS_OUT3, ws + WS_P3,
        ws + WS_STATS + 16, bn3g, bn3b, 1.0f / 524288.0f);
    fc_kernel<<<256, 256, 0, stream>>>(ws + WS_P3, ws + WS_WFC, fcb, outp);
}

// Round 6
// 185.057 us; speedup vs baseline: 5.2186x; 1.0315x over previous
//
#include <hip/hip_runtime.h>
#include <math.h>

// ---------------- workspace layout (float offsets) ----------------
#define WS_STATS 0         // 24 floats: [layer][S_r..S_k, Q_r..Q_k]
#define WS_W1    32        // 16*4*9   = 576      layout [s(4)][k(9)][oc(16)]
#define WS_W2    640       // 64*16*9  = 9216     layout [ic(16)][k(9)][oc(64)]
#define WS_W3    9856      // 128*64*9 = 73728    layout [ic(64)][k(9)][oc(128)]
#define WS_WFC   83584     // 2048*16  = 32768    layout [row(2048)][col(16)]
#define WS_POOL  116352    // 256*200  = 51200
#define WS_OUT1  167552    // 256*16*32*32 = 4194304
#define WS_OUT2  4361856   // 256*64*16*16 = 4194304
#define WS_OUT3  8556160   // 256*128*8*8  = 2097152
// total = 10653312 floats = 40.6 MiB

// Hamilton block table: T[a][b] -> (component, sign)
__device__ const int   d_TC[4][4] = {{0,1,2,3},{1,0,3,2},{2,3,0,1},{3,2,1,0}};
__device__ const float d_TS[4][4] = {{1.f,-1.f,-1.f,-1.f},{1.f,1.f,-1.f,1.f},
                                     {1.f,1.f,1.f,-1.f},{1.f,-1.f,1.f,1.f}};

// ---------------- fused: global-avg-pool (blocks 0..51199) + weight prep (last 512) ----
__global__ __launch_bounds__(256) void prepmean_kernel(
    const float* __restrict__ x, float* __restrict__ pooled,
    const float* l1r, const float* l1i, const float* l1j, const float* l1k,
    const float* l2r, const float* l2i, const float* l2j, const float* l2k,
    const float* l3r, const float* l3i, const float* l3j, const float* l3k,
    const float* fcr, const float* fci, const float* fcj, const float* fck,
    float* ws)
{
    __shared__ float red[4];
    int bid = blockIdx.x;
    int t = threadIdx.x;
    if (bid < 51200) {
        const float4* src = reinterpret_cast<const float4*>(x + (size_t)bid * 1024);
        float4 v = src[t];
        float s = v.x + v.y + v.z + v.w;
        #pragma unroll
        for (int off = 32; off; off >>= 1) s += __shfl_xor(s, off, 64);
        if ((t & 63) == 0) red[t >> 6] = s;
        __syncthreads();
        if (t == 0) pooled[bid] = (red[0] + red[1] + red[2] + red[3]) * (1.0f / 1024.0f);
        return;
    }
    int tid = (bid - 51200) * 256 + t;
    const int nthr = 512 * 256;
    if (tid < 24) ws[WS_STATS + tid] = 0.f;

    { // W1: [s(4)][k(9)][oc(16)]
        const float* cp[4] = {l1r, l1i, l1j, l1k};
        for (int e = tid; e < 576; e += nthr) {
            int s = e / 144, rem = e % 144, k = rem / 16, oc = rem % 16;
            int p = oc >> 2, o = oc & 3;
            ws[WS_W1 + e] = d_TS[p][s] * cp[d_TC[p][s]][o * 9 + k];
        }
    }
    { // W2: [ic(16)][k(9)][oc(64)]
        const float* cp[4] = {l2r, l2i, l2j, l2k};
        for (int e = tid; e < 9216; e += nthr) {
            int oc = e & 63, k = (e >> 6) % 9, ic = e / 576;
            int p = oc >> 4, o = oc & 15, s = ic >> 2, ii = ic & 3;
            ws[WS_W2 + e] = d_TS[p][s] * cp[d_TC[p][s]][(o * 4 + ii) * 9 + k];
        }
    }
    { // W3: [ic(64)][k(9)][oc(128)]
        const float* cp[4] = {l3r, l3i, l3j, l3k};
        for (int e = tid; e < 73728; e += nthr) {
            int oc = e & 127, k = (e >> 7) % 9, ic = e / 1152;
            int p = oc >> 5, o = oc & 31, s = ic >> 4, ii = ic & 15;
            ws[WS_W3 + e] = d_TS[p][s] * cp[d_TC[p][s]][(o * 16 + ii) * 9 + k];
        }
    }
    { // WFC: 2048 x 16 from (512,4) components
        const float* cp[4] = {fcr, fci, fcj, fck};
        for (int e = tid; e < 32768; e += nthr) {
            int R = e >> 4, C = e & 15;
            int p = R >> 9, rr = R & 511, q = C >> 2, cc = C & 3;
            ws[WS_WFC + e] = d_TS[q][p] * cp[d_TC[q][p]][rr * 4 + cc];
        }
    }
}

// ---------------- conv1 (+in-block top-3): 4->16 ch, 32x32; grid 2048 ----
__global__ __launch_bounds__(256) void conv1_kernel(const float* __restrict__ x,
                                                    const float* __restrict__ pooled,
                                                    const float* __restrict__ w_eca,
                                                    const float* __restrict__ W1,
                                                    const float* __restrict__ b1,
                                                    float* __restrict__ out1,
                                                    float* __restrict__ stats)
{
    __shared__ float smem[3][6][36];
    __shared__ float rs[8];
    __shared__ int idx_s[3];
    int b = blockIdx.x >> 3, rg = blockIdx.x & 7;
    int t = threadIdx.x;
    if (t < 8) rs[t] = 0.f;
    if (t < 64) {  // wave-0 top-3 (tie -> lowest idx), monotonic in w*pooled
        float w = w_eca[0];
        float v[4]; int c[4];
        #pragma unroll
        for (int i = 0; i < 4; i++) {
            int ch = t + 64 * i;
            c[i] = ch;
            v[i] = (ch < 200) ? w * pooled[b * 200 + ch] : -INFINITY;
        }
        for (int k = 0; k < 3; k++) {
            float bv = -INFINITY; int bi = 0x3fffffff;
            #pragma unroll
            for (int i = 0; i < 4; i++)
                if (v[i] > bv || (v[i] == bv && c[i] < bi)) { bv = v[i]; bi = c[i]; }
            for (int off = 32; off; off >>= 1) {
                float ov = __shfl_xor(bv, off, 64);
                int   oi = __shfl_xor(bi, off, 64);
                if (ov > bv || (ov == bv && oi < bi)) { bv = ov; bi = oi; }
            }
            if (t == 0) idx_s[k] = bi;
            #pragma unroll
            for (int i = 0; i < 4; i++) if (c[i] == bi) v[i] = -INFINITY;
        }
    }
    __syncthreads();
    for (int i = t; i < 648; i += 256) {
        int s = i / 216, rem = i % 216, r = rem / 36, cc = rem % 36;
        int gr = rg * 4 - 1 + r, gc = cc - 1;
        float v = 0.f;
        if (gr >= 0 && gr < 32 && gc >= 0 && gc < 32)
            v = x[((size_t)b * 200 + idx_s[s]) * 1024 + gr * 32 + gc];
        smem[s][r][cc] = v;
    }
    __syncthreads();

    int oc = t & 15, rp = (t >> 4) & 3, ch = t >> 6;
    float bb = b1[oc];
    float acc[8];
    #pragma unroll
    for (int px = 0; px < 8; px++) acc[px] = bb;

    #pragma unroll
    for (int s = 0; s < 3; s++) {
        float w[9];
        #pragma unroll
        for (int k = 0; k < 9; k++) w[k] = W1[((s + 1) * 9 + k) * 16 + oc];
        float rowv[3][12];
        #pragma unroll
        for (int dy = 0; dy < 3; dy++) {
            const float* rb = &smem[s][rp + dy][ch * 8];
            float4 a = *reinterpret_cast<const float4*>(rb);
            float4 bq = *reinterpret_cast<const float4*>(rb + 4);
            float4 cq = *reinterpret_cast<const float4*>(rb + 8);
            rowv[dy][0]=a.x;  rowv[dy][1]=a.y;  rowv[dy][2]=a.z;  rowv[dy][3]=a.w;
            rowv[dy][4]=bq.x; rowv[dy][5]=bq.y; rowv[dy][6]=bq.z; rowv[dy][7]=bq.w;
            rowv[dy][8]=cq.x; rowv[dy][9]=cq.y; rowv[dy][10]=cq.z; rowv[dy][11]=cq.w;
        }
        #pragma unroll
        for (int dy = 0; dy < 3; dy++)
            #pragma unroll
            for (int px = 0; px < 8; px++) {
                float a = acc[px];
                a = fmaf(w[dy*3+0], rowv[dy][px],   a);
                a = fmaf(w[dy*3+1], rowv[dy][px+1], a);
                a = fmaf(w[dy*3+2], rowv[dy][px+2], a);
                acc[px] = a;
            }
    }
    int row = rg * 4 + rp;
    float* outb = out1 + ((size_t)b * 16 + oc) * 1024 + row * 32 + ch * 8;
    *reinterpret_cast<float4*>(outb)     = make_float4(acc[0], acc[1], acc[2], acc[3]);
    *reinterpret_cast<float4*>(outb + 4) = make_float4(acc[4], acc[5], acc[6], acc[7]);
    float sv = 0.f, qv = 0.f;
    #pragma unroll
    for (int px = 0; px < 8; px++) { sv += acc[px]; qv += acc[px] * acc[px]; }
    int g = oc >> 2;
    atomicAdd(&rs[g], sv); atomicAdd(&rs[4 + g], qv);
    __syncthreads();
    if (t < 8) atomicAdd(&stats[t], rs[t]);
}

// ---------------- conv2 (+fused bn1/relu/pool staging): 16->64 ch, 16x16; grid 2048 ----
__global__ __launch_bounds__(256) void conv2_kernel(const float* __restrict__ out1,
                                                    const float* __restrict__ W2,
                                                    const float* __restrict__ b2,
                                                    const float* __restrict__ bn1g,
                                                    const float* __restrict__ bn1b,
                                                    float* __restrict__ out2,
                                                    float* __restrict__ stats)
{
    __shared__ float smem[16][4][20];
    __shared__ float rs[8];
    __shared__ float sc[16], sh[16];
    int b = blockIdx.x >> 3, rq = blockIdx.x & 7;
    int t = threadIdx.x;
    if (t < 8) rs[t] = 0.f;
    if (t < 16) {
        const float invN = 1.0f / 1048576.0f;
        float var = 0.f;
        #pragma unroll
        for (int g = 0; g < 4; g++) {
            float S = stats[g], Q = stats[4 + g];
            var += Q - S * S * invN;
        }
        var *= invN;
        float inv = 1.0f / sqrtf(var + 1e-5f);
        float scale = bn1g[t & 3] * inv;
        sc[t] = scale;
        sh[t] = bn1b[t] - stats[t >> 2] * invN * scale;
    }
    __syncthreads();
    for (int i = t; i < 1280; i += 256) {
        int ic = i / 80, rem = i % 80, r = rem / 20, cc = rem % 20;
        int gr = rq * 2 - 1 + r, gc = cc - 1;
        float v = 0.f;
        if (gr >= 0 && gr < 16 && gc >= 0 && gc < 16) {
            const float* base = out1 + ((size_t)(b * 16 + ic) * 32 + 2 * gr) * 32 + 2 * gc;
            float2 a = *reinterpret_cast<const float2*>(base);
            float2 d = *reinterpret_cast<const float2*>(base + 32);
            float s0 = sc[ic], s1 = sh[ic];
            v = 0.25f * (fmaxf(fmaf(a.x, s0, s1), 0.f) + fmaxf(fmaf(a.y, s0, s1), 0.f)
                       + fmaxf(fmaf(d.x, s0, s1), 0.f) + fmaxf(fmaf(d.y, s0, s1), 0.f));
        }
        smem[ic][r][cc] = v;
    }
    __syncthreads();

    int oc = t & 63, rp = (t >> 6) & 1, ch = t >> 7;
    float bb = b2[oc];
    float acc[8];
    #pragma unroll
    for (int px = 0; px < 8; px++) acc[px] = bb;

    const float* Wp = W2 + oc;
    float w[9], wn[9];
    #pragma unroll
    for (int k = 0; k < 9; k++) w[k] = Wp[k * 64];
    for (int ic = 0; ic < 16; ic++) {
        if (ic < 15) {
            #pragma unroll
            for (int k = 0; k < 9; k++) wn[k] = Wp[(ic + 1) * 576 + k * 64];
        }
        float rowv[3][12];
        #pragma unroll
        for (int dy = 0; dy < 3; dy++) {
            const float* rb = &smem[ic][rp + dy][ch * 8];
            float4 a = *reinterpret_cast<const float4*>(rb);
            float4 bq = *reinterpret_cast<const float4*>(rb + 4);
            float4 cq = *reinterpret_cast<const float4*>(rb + 8);
            rowv[dy][0]=a.x;  rowv[dy][1]=a.y;  rowv[dy][2]=a.z;  rowv[dy][3]=a.w;
            rowv[dy][4]=bq.x; rowv[dy][5]=bq.y; rowv[dy][6]=bq.z; rowv[dy][7]=bq.w;
            rowv[dy][8]=cq.x; rowv[dy][9]=cq.y; rowv[dy][10]=cq.z; rowv[dy][11]=cq.w;
        }
        #pragma unroll
        for (int dy = 0; dy < 3; dy++)
            #pragma unroll
            for (int px = 0; px < 8; px++) {
                float a = acc[px];
                a = fmaf(w[dy*3+0], rowv[dy][px],   a);
                a = fmaf(w[dy*3+1], rowv[dy][px+1], a);
                a = fmaf(w[dy*3+2], rowv[dy][px+2], a);
                acc[px] = a;
            }
        if (ic < 15) {
            #pragma unroll
            for (int k = 0; k < 9; k++) w[k] = wn[k];
        }
    }
    int row = rq * 2 + rp;
    float* outb = out2 + ((size_t)b * 64 + oc) * 256 + row * 16 + ch * 8;
    *reinterpret_cast<float4*>(outb)     = make_float4(acc[0], acc[1], acc[2], acc[3]);
    *reinterpret_cast<float4*>(outb + 4) = make_float4(acc[4], acc[5], acc[6], acc[7]);
    float sv = 0.f, qv = 0.f;
    #pragma unroll
    for (int px = 0; px < 8; px++) { sv += acc[px]; qv += acc[px] * acc[px]; }
    int g = oc >> 4;
    atomicAdd(&rs[g], sv); atomicAdd(&rs[4 + g], qv);
    __syncthreads();
    if (t < 8) atomicAdd(&stats[8 + t], rs[t]);
}

// ---------------- conv3 (+fused bn2/relu/pool staging): 64->128 ch, 8x8; grid 1024 ----
__global__ __launch_bounds__(256) void conv3_kernel(const float* __restrict__ out2,
                                                    const float* __restrict__ W3,
                                                    const float* __restrict__ b3,
                                                    const float* __restrict__ bn2g,
                                                    const float* __restrict__ bn2b,
                                                    float* __restrict__ out3,
                                                    float* __restrict__ stats)
{
    __shared__ float smem[64][4][12];
    __shared__ float rs[8];
    __shared__ float sc[64], sh[64];
    int b = blockIdx.x >> 2, rh = blockIdx.x & 3;
    int t = threadIdx.x;
    if (t < 8) rs[t] = 0.f;
    if (t < 64) {
        const float invN = 1.0f / 1048576.0f;
        float var = 0.f;
        #pragma unroll
        for (int g = 0; g < 4; g++) {
            float S = stats[8 + g], Q = stats[12 + g];
            var += Q - S * S * invN;
        }
        var *= invN;
        float inv = 1.0f / sqrtf(var + 1e-5f);
        float scale = bn2g[t & 15] * inv;
        sc[t] = scale;
        sh[t] = bn2b[t] - stats[8 + (t >> 4)] * invN * scale;
    }
    __syncthreads();
    for (int i = t; i < 3072; i += 256) {
        int ic = i / 48, rem = i % 48, r = rem / 12, cc = rem % 12;
        int gr = rh * 2 - 1 + r, gc = cc - 1;
        float v = 0.f;
        if (gr >= 0 && gr < 8 && gc >= 0 && gc < 8) {
            const float* base = out2 + ((size_t)(b * 64 + ic) * 16 + 2 * gr) * 16 + 2 * gc;
            float2 a = *reinterpret_cast<const float2*>(base);
            float2 d = *reinterpret_cast<const float2*>(base + 16);
            float s0 = sc[ic], s1 = sh[ic];
            v = 0.25f * (fmaxf(fmaf(a.x, s0, s1), 0.f) + fmaxf(fmaf(a.y, s0, s1), 0.f)
                       + fmaxf(fmaf(d.x, s0, s1), 0.f) + fmaxf(fmaf(d.y, s0, s1), 0.f));
        }
        smem[ic][r][cc] = v;
    }
    __syncthreads();

    int oc = t & 127, rp = t >> 7;
    float bb = b3[oc];
    float acc[8];
    #pragma unroll
    for (int px = 0; px < 8; px++) acc[px] = bb;

    const float* Wp = W3 + oc;
    float w[9], wn[9];
    #pragma unroll
    for (int k = 0; k < 9; k++) w[k] = Wp[k * 128];
    for (int ic = 0; ic < 64; ic++) {
        if (ic < 63) {
            #pragma unroll
            for (int k = 0; k < 9; k++) wn[k] = Wp[(ic + 1) * 1152 + k * 128];
        }
        float rowv[3][12];
        #pragma unroll
        for (int dy = 0; dy < 3; dy++) {
            const float* rb = &smem[ic][rp + dy][0];
            float4 a = *reinterpret_cast<const float4*>(rb);
            float4 bq = *reinterpret_cast<const float4*>(rb + 4);
            float4 cq = *reinterpret_cast<const float4*>(rb + 8);
            rowv[dy][0]=a.x;  rowv[dy][1]=a.y;  rowv[dy][2]=a.z;  rowv[dy][3]=a.w;
            rowv[dy][4]=bq.x; rowv[dy][5]=bq.y; rowv[dy][6]=bq.z; rowv[dy][7]=bq.w;
            rowv[dy][8]=cq.x; rowv[dy][9]=cq.y; rowv[dy][10]=cq.z; rowv[dy][11]=cq.w;
        }
        #pragma unroll
        for (int dy = 0; dy < 3; dy++)
            #pragma unroll
            for (int px = 0; px < 8; px++) {
                float a = acc[px];
                a = fmaf(w[dy*3+0], rowv[dy][px],   a);
                a = fmaf(w[dy*3+1], rowv[dy][px+1], a);
                a = fmaf(w[dy*3+2], rowv[dy][px+2], a);
                acc[px] = a;
            }
        if (ic < 63) {
            #pragma unroll
            for (int k = 0; k < 9; k++) w[k] = wn[k];
        }
    }
    int row = rh * 2 + rp;
    float* outb = out3 + ((size_t)b * 128 + oc) * 64 + row * 8;
    *reinterpret_cast<float4*>(outb)     = make_float4(acc[0], acc[1], acc[2], acc[3]);
    *reinterpret_cast<float4*>(outb + 4) = make_float4(acc[4], acc[5], acc[6], acc[7]);
    float sv = 0.f, qv = 0.f;
    #pragma unroll
    for (int px = 0; px < 8; px++) { sv += acc[px]; qv += acc[px] * acc[px]; }
    int g = oc >> 5;
    atomicAdd(&rs[g], sv); atomicAdd(&rs[4 + g], qv);
    __syncthreads();
    if (t < 8) atomicAdd(&stats[16 + t], rs[t]);
}

// ---------------- fc (+fused bn3/relu/pool staging): [256,2048]@[2048,16]+b ----
__global__ __launch_bounds__(256) void fc_kernel(const float* __restrict__ out3,
                                                 const float* __restrict__ WFC,
                                                 const float* __restrict__ fcb,
                                                 const float* __restrict__ bn3g,
                                                 const float* __restrict__ bn3b,
                                                 const float* __restrict__ stats,
                                                 float* __restrict__ out)
{
    __shared__ float p3s[2048];
    __shared__ float sc[128], sh[128];
    __shared__ float red[256];
    int b = blockIdx.x, t = threadIdx.x;
    if (t < 128) {
        const float invN = 1.0f / 524288.0f;
        float var = 0.f;
        #pragma unroll
        for (int g = 0; g < 4; g++) {
            float S = stats[16 + g], Q = stats[20 + g];
            var += Q - S * S * invN;
        }
        var *= invN;
        float inv = 1.0f / sqrtf(var + 1e-5f);
        float scale = bn3g[t & 31] * inv;
        sc[t] = scale;
        sh[t] = bn3b[t] - stats[16 + (t >> 5)] * invN * scale;
    }
    __syncthreads();
    for (int i = t; i < 2048; i += 256) {
        int c = i >> 4, rem = i & 15, pr = rem >> 2, pc = rem & 3;
        const float* base = out3 + ((size_t)(b * 128 + c) * 8 + 2 * pr) * 8 + 2 * pc;
        float2 a = *reinterpret_cast<const float2*>(base);
        float2 d = *reinterpret_cast<const float2*>(base + 8);
        float s0 = sc[c], s1 = sh[c];
        p3s[i] = 0.25f * (fmaxf(fmaf(a.x, s0, s1), 0.f) + fmaxf(fmaf(a.y, s0, s1), 0.f)
                        + fmaxf(fmaf(d.x, s0, s1), 0.f) + fmaxf(fmaf(d.y, s0, s1), 0.f));
    }
    __syncthreads();
    int col = t & 15, fr = t >> 4;
    float s = 0.f;
    for (int i = 0; i < 128; i++) {
        int f = i * 16 + fr;
        s = fmaf(p3s[f], WFC[f * 16 + col], s);
    }
    red[t] = s;
    __syncthreads();
    for (int st = 128; st >= 16; st >>= 1) {
        if (t < st) red[t] += red[t + st];
        __syncthreads();
    }
    if (t < 16) out[b * 16 + t] = red[t] + fcb[t];
}

// ---------------- launch ----------------
extern "C" void kernel_launch(void* const* d_in, const int* in_sizes, int n_in,
                              void* d_out, int out_size, void* d_ws, size_t ws_size,
                              hipStream_t stream)
{
    (void)in_sizes; (void)n_in; (void)out_size; (void)ws_size;
    const float* x     = (const float*)d_in[0];
    const float* w_eca = (const float*)d_in[1];
    const float* l1r = (const float*)d_in[2],  *l1i = (const float*)d_in[3];
    const float* l1j = (const float*)d_in[4],  *l1k = (const float*)d_in[5];
    const float* l1b = (const float*)d_in[6];
    const float* bn1g = (const float*)d_in[7], *bn1b = (const float*)d_in[8];
    const float* l2r = (const float*)d_in[9],  *l2i = (const float*)d_in[10];
    const float* l2j = (const float*)d_in[11], *l2k = (const float*)d_in[12];
    const float* l2b = (const float*)d_in[13];
    const float* bn2g = (const float*)d_in[14], *bn2b = (const float*)d_in[15];
    const float* l3r = (const float*)d_in[16], *l3i = (const float*)d_in[17];
    const float* l3j = (const float*)d_in[18], *l3k = (const float*)d_in[19];
    const float* l3b = (const float*)d_in[20];
    const float* bn3g = (const float*)d_in[21], *bn3b = (const float*)d_in[22];
    const float* fcr = (const float*)d_in[23], *fci = (const float*)d_in[24];
    const float* fcj = (const float*)d_in[25], *fck = (const float*)d_in[26];
    const float* fcb = (const float*)d_in[27];

    float* ws   = (float*)d_ws;
    float* outp = (float*)d_out;

    prepmean_kernel<<<51712, 256, 0, stream>>>(x, ws + WS_POOL,
        l1r, l1i, l1j, l1k, l2r, l2i, l2j, l2k, l3r, l3i, l3j, l3k,
        fcr, fci, fcj, fck, ws);
    conv1_kernel<<<2048, 256, 0, stream>>>(x, ws + WS_POOL, w_eca, ws + WS_W1,
                                           l1b, ws + WS_OUT1, ws + WS_STATS);
    conv2_kernel<<<2048, 256, 0, stream>>>(ws + WS_OUT1, ws + WS_W2, l2b, bn1g, bn1b,
                                           ws + WS_OUT2, ws + WS_STATS);
    conv3_kernel<<<1024, 256, 0, stream>>>(ws + WS_OUT2, ws + WS_W3, l3b, bn2g, bn2b,
                                           ws + WS_OUT3, ws + WS_STATS);
    fc_kernel<<<256, 256, 0, stream>>>(ws + WS_OUT3, ws + WS_WFC, fcb, bn3g, bn3b,
                                       ws + WS_STATS, outp);
}

// Round 8
// 184.978 us; speedup vs baseline: 5.2208x; 1.0004x over previous
//
#include <hip/hip_runtime.h>
#include <math.h>

// ---------------- workspace layout (float offsets) ----------------
#define WS_STATS 0         // 24 floats: [layer][S_r..S_k, Q_r..Q_k]
#define WS_W1    32        // 16*4*9   = 576      layout [s(4)][k(9)][oc(16)]
#define WS_W2    640       // 64*16*9  = 9216     layout [ic(16)][k(9)][oc(64)]
#define WS_W3    9856      // 128*64*9 = 73728    layout [ic(64)][k(9)][oc(128)]
#define WS_WFC   83584     // 2048*16  = 32768    layout [row(2048)][col(16)]
#define WS_POOL  116352    // 256*200  = 51200
#define WS_OUT1  167552    // 256*16*32*32 = 4194304
#define WS_OUT2  4361856   // 256*64*16*16 = 4194304
#define WS_OUT3  8556160   // 256*128*8*8  = 2097152

// Hamilton block table: T[a][b] -> (component, sign)
__device__ const int   d_TC[4][4] = {{0,1,2,3},{1,0,3,2},{2,3,0,1},{3,2,1,0}};
__device__ const float d_TS[4][4] = {{1.f,-1.f,-1.f,-1.f},{1.f,1.f,-1.f,1.f},
                                     {1.f,1.f,1.f,-1.f},{1.f,-1.f,1.f,1.f}};

// ---------------- persistent prep+mean: grid 1024, 50 channels/block ----------------
__global__ __launch_bounds__(256) void prepmean_kernel(
    const float* __restrict__ x, float* __restrict__ pooled,
    const float* l1r, const float* l1i, const float* l1j, const float* l1k,
    const float* l2r, const float* l2i, const float* l2j, const float* l2k,
    const float* l3r, const float* l3i, const float* l3j, const float* l3k,
    const float* fcr, const float* fci, const float* fcj, const float* fck,
    float* ws)
{
    const int blk = blockIdx.x, t = threadIdx.x;
    const int lane = t & 63, wv = t >> 6;
    int tid = blk * 256 + t;
    const int nthr = 1024 * 256;
    if (tid < 24) ws[WS_STATS + tid] = 0.f;

    { // W1: [s(4)][k(9)][oc(16)]
        const float* cp[4] = {l1r, l1i, l1j, l1k};
        for (int e = tid; e < 576; e += nthr) {
            int s = e / 144, rem = e % 144, k = rem / 16, oc = rem % 16;
            int p = oc >> 2, o = oc & 3;
            ws[WS_W1 + e] = d_TS[p][s] * cp[d_TC[p][s]][o * 9 + k];
        }
    }
    { // W2: [ic(16)][k(9)][oc(64)]
        const float* cp[4] = {l2r, l2i, l2j, l2k};
        for (int e = tid; e < 9216; e += nthr) {
            int oc = e & 63, k = (e >> 6) % 9, ic = e / 576;
            int p = oc >> 4, o = oc & 15, s = ic >> 2, ii = ic & 3;
            ws[WS_W2 + e] = d_TS[p][s] * cp[d_TC[p][s]][(o * 4 + ii) * 9 + k];
        }
    }
    { // W3: [ic(64)][k(9)][oc(128)]
        const float* cp[4] = {l3r, l3i, l3j, l3k};
        for (int e = tid; e < 73728; e += nthr) {
            int oc = e & 127, k = (e >> 7) % 9, ic = e / 1152;
            int p = oc >> 5, o = oc & 31, s = ic >> 4, ii = ic & 15;
            ws[WS_W3 + e] = d_TS[p][s] * cp[d_TC[p][s]][(o * 16 + ii) * 9 + k];
        }
    }
    { // WFC: 2048 x 16
        const float* cp[4] = {fcr, fci, fcj, fck};
        for (int e = tid; e < 32768; e += nthr) {
            int R = e >> 4, C = e & 15;
            int p = R >> 9, rr = R & 511, q = C >> 2, cc = C & 3;
            ws[WS_WFC + e] = d_TS[q][p] * cp[d_TC[q][p]][rr * 4 + cc];
        }
    }
    // channel means: 50 channels per block, one channel per wave-iteration
    int base = blk * 50;
    for (int i = wv; i < 50; i += 4) {
        const float4* src = reinterpret_cast<const float4*>(x + (size_t)(base + i) * 1024);
        float s = 0.f;
        #pragma unroll
        for (int j = 0; j < 4; j++) {
            float4 v = src[lane + 64 * j];
            s += v.x + v.y + v.z + v.w;
        }
        #pragma unroll
        for (int off = 32; off; off >>= 1) s += __shfl_xor(s, off, 64);
        if (lane == 0) pooled[base + i] = s * (1.0f / 1024.0f);
    }
}

// ---------------- conv1 (+in-block top-3): 4->16 ch, 32x32; grid 2048 ----
__global__ __launch_bounds__(256) void conv1_kernel(const float* __restrict__ x,
                                                    const float* __restrict__ pooled,
                                                    const float* __restrict__ w_eca,
                                                    const float* __restrict__ W1,
                                                    const float* __restrict__ b1,
                                                    float* __restrict__ out1,
                                                    float* __restrict__ stats)
{
    __shared__ float smem[3][6][36];
    __shared__ float rs[8];
    __shared__ int idx_s[3];
    int b = blockIdx.x >> 3, rg = blockIdx.x & 7;
    int t = threadIdx.x;
    if (t < 8) rs[t] = 0.f;
    if (t < 64) {  // wave-0 top-3 (tie -> lowest idx), monotonic in w*pooled
        float w = w_eca[0];
        float v[4]; int c[4];
        #pragma unroll
        for (int i = 0; i < 4; i++) {
            int ch = t + 64 * i;
            c[i] = ch;
            v[i] = (ch < 200) ? w * pooled[b * 200 + ch] : -INFINITY;
        }
        for (int k = 0; k < 3; k++) {
            float bv = -INFINITY; int bi = 0x3fffffff;
            #pragma unroll
            for (int i = 0; i < 4; i++)
                if (v[i] > bv || (v[i] == bv && c[i] < bi)) { bv = v[i]; bi = c[i]; }
            for (int off = 32; off; off >>= 1) {
                float ov = __shfl_xor(bv, off, 64);
                int   oi = __shfl_xor(bi, off, 64);
                if (ov > bv || (ov == bv && oi < bi)) { bv = ov; bi = oi; }
            }
            if (t == 0) idx_s[k] = bi;
            #pragma unroll
            for (int i = 0; i < 4; i++) if (c[i] == bi) v[i] = -INFINITY;
        }
    }
    __syncthreads();
    for (int i = t; i < 648; i += 256) {
        int s = i / 216, rem = i % 216, r = rem / 36, cc = rem % 36;
        int gr = rg * 4 - 1 + r, gc = cc - 1;
        float v = 0.f;
        if (gr >= 0 && gr < 32 && gc >= 0 && gc < 32)
            v = x[((size_t)b * 200 + idx_s[s]) * 1024 + gr * 32 + gc];
        smem[s][r][cc] = v;
    }
    __syncthreads();

    int oc = t & 15, rp = (t >> 4) & 3, ch = t >> 6;
    float bb = b1[oc];
    float acc[8];
    #pragma unroll
    for (int px = 0; px < 8; px++) acc[px] = bb;

    #pragma unroll
    for (int s = 0; s < 3; s++) {
        float w[9];
        #pragma unroll
        for (int k = 0; k < 9; k++) w[k] = W1[((s + 1) * 9 + k) * 16 + oc];
        float rowv[3][12];
        #pragma unroll
        for (int dy = 0; dy < 3; dy++) {
            const float* rb = &smem[s][rp + dy][ch * 8];
            float4 a = *reinterpret_cast<const float4*>(rb);
            float4 bq = *reinterpret_cast<const float4*>(rb + 4);
            float4 cq = *reinterpret_cast<const float4*>(rb + 8);
            rowv[dy][0]=a.x;  rowv[dy][1]=a.y;  rowv[dy][2]=a.z;  rowv[dy][3]=a.w;
            rowv[dy][4]=bq.x; rowv[dy][5]=bq.y; rowv[dy][6]=bq.z; rowv[dy][7]=bq.w;
            rowv[dy][8]=cq.x; rowv[dy][9]=cq.y; rowv[dy][10]=cq.z; rowv[dy][11]=cq.w;
        }
        #pragma unroll
        for (int dy = 0; dy < 3; dy++)
            #pragma unroll
            for (int px = 0; px < 8; px++) {
                float a = acc[px];
                a = fmaf(w[dy*3+0], rowv[dy][px],   a);
                a = fmaf(w[dy*3+1], rowv[dy][px+1], a);
                a = fmaf(w[dy*3+2], rowv[dy][px+2], a);
                acc[px] = a;
            }
    }
    int row = rg * 4 + rp;
    float* outb = out1 + ((size_t)b * 16 + oc) * 1024 + row * 32 + ch * 8;
    *reinterpret_cast<float4*>(outb)     = make_float4(acc[0], acc[1], acc[2], acc[3]);
    *reinterpret_cast<float4*>(outb + 4) = make_float4(acc[4], acc[5], acc[6], acc[7]);
    float sv = 0.f, qv = 0.f;
    #pragma unroll
    for (int px = 0; px < 8; px++) { sv += acc[px]; qv += acc[px] * acc[px]; }
    int g = oc >> 2;
    atomicAdd(&rs[g], sv); atomicAdd(&rs[4 + g], qv);
    __syncthreads();
    if (t < 8) atomicAdd(&stats[t], rs[t]);
}

// ---------------- conv2 (+fused bn1/relu/pool staging): 16->64 ch, 16x16; grid 2048 ----
__global__ __launch_bounds__(256) void conv2_kernel(const float* __restrict__ out1,
                                                    const float* __restrict__ W2,
                                                    const float* __restrict__ b2,
                                                    const float* __restrict__ bn1g,
                                                    const float* __restrict__ bn1b,
                                                    float* __restrict__ out2,
                                                    float* __restrict__ stats)
{
    __shared__ float smem[16][4][20];
    __shared__ float rs[8];
    __shared__ float sc[16], sh[16];
    int b = blockIdx.x >> 3, rq = blockIdx.x & 7;
    int t = threadIdx.x;
    if (t < 8) rs[t] = 0.f;
    if (t < 16) {
        const float invN = 1.0f / 1048576.0f;
        float var = 0.f;
        #pragma unroll
        for (int g = 0; g < 4; g++) {
            float S = stats[g], Q = stats[4 + g];
            var += Q - S * S * invN;
        }
        var *= invN;
        float inv = 1.0f / sqrtf(var + 1e-5f);
        float scale = bn1g[t & 3] * inv;
        sc[t] = scale;
        sh[t] = bn1b[t] - stats[t >> 2] * invN * scale;
    }
    __syncthreads();
    for (int i = t; i < 1280; i += 256) {
        int ic = i / 80, rem = i % 80, r = rem / 20, cc = rem % 20;
        int gr = rq * 2 - 1 + r, gc = cc - 1;
        float v = 0.f;
        if (gr >= 0 && gr < 16 && gc >= 0 && gc < 16) {
            const float* base = out1 + ((size_t)(b * 16 + ic) * 32 + 2 * gr) * 32 + 2 * gc;
            float2 a = *reinterpret_cast<const float2*>(base);
            float2 d = *reinterpret_cast<const float2*>(base + 32);
            float s0 = sc[ic], s1 = sh[ic];
            v = 0.25f * (fmaxf(fmaf(a.x, s0, s1), 0.f) + fmaxf(fmaf(a.y, s0, s1), 0.f)
                       + fmaxf(fmaf(d.x, s0, s1), 0.f) + fmaxf(fmaf(d.y, s0, s1), 0.f));
        }
        smem[ic][r][cc] = v;
    }
    __syncthreads();

    int oc = t & 63, rp = (t >> 6) & 1, ch = t >> 7;
    float bb = b2[oc];
    float acc[8];
    #pragma unroll
    for (int px = 0; px < 8; px++) acc[px] = bb;

    const float* Wp = W2 + oc;
    float w[9], wn[9];
    #pragma unroll
    for (int k = 0; k < 9; k++) w[k] = Wp[k * 64];
    for (int ic = 0; ic < 16; ic++) {
        if (ic < 15) {
            #pragma unroll
            for (int k = 0; k < 9; k++) wn[k] = Wp[(ic + 1) * 576 + k * 64];
        }
        float rowv[3][12];
        #pragma unroll
        for (int dy = 0; dy < 3; dy++) {
            const float* rb = &smem[ic][rp + dy][ch * 8];
            float4 a = *reinterpret_cast<const float4*>(rb);
            float4 bq = *reinterpret_cast<const float4*>(rb + 4);
            float4 cq = *reinterpret_cast<const float4*>(rb + 8);
            rowv[dy][0]=a.x;  rowv[dy][1]=a.y;  rowv[dy][2]=a.z;  rowv[dy][3]=a.w;
            rowv[dy][4]=bq.x; rowv[dy][5]=bq.y; rowv[dy][6]=bq.z; rowv[dy][7]=bq.w;
            rowv[dy][8]=cq.x; rowv[dy][9]=cq.y; rowv[dy][10]=cq.z; rowv[dy][11]=cq.w;
        }
        #pragma unroll
        for (int dy = 0; dy < 3; dy++)
            #pragma unroll
            for (int px = 0; px < 8; px++) {
                float a = acc[px];
                a = fmaf(w[dy*3+0], rowv[dy][px],   a);
                a = fmaf(w[dy*3+1], rowv[dy][px+1], a);
                a = fmaf(w[dy*3+2], rowv[dy][px+2], a);
                acc[px] = a;
            }
        if (ic < 15) {
            #pragma unroll
            for (int k = 0; k < 9; k++) w[k] = wn[k];
        }
    }
    int row = rq * 2 + rp;
    float* outb = out2 + ((size_t)b * 64 + oc) * 256 + row * 16 + ch * 8;
    *reinterpret_cast<float4*>(outb)     = make_float4(acc[0], acc[1], acc[2], acc[3]);
    *reinterpret_cast<float4*>(outb + 4) = make_float4(acc[4], acc[5], acc[6], acc[7]);
    float sv = 0.f, qv = 0.f;
    #pragma unroll
    for (int px = 0; px < 8; px++) { sv += acc[px]; qv += acc[px] * acc[px]; }
    int g = oc >> 4;
    atomicAdd(&rs[g], sv); atomicAdd(&rs[4 + g], qv);
    __syncthreads();
    if (t < 8) atomicAdd(&stats[8 + t], rs[t]);
}

// ---------------- conv3 (+fused bn2/relu/pool staging): 64->128 ch, 8x8; grid 1024 ----
__global__ __launch_bounds__(256) void conv3_kernel(const float* __restrict__ out2,
                                                    const float* __restrict__ W3,
                                                    const float* __restrict__ b3,
                                                    const float* __restrict__ bn2g,
                                                    const float* __restrict__ bn2b,
                                                    float* __restrict__ out3,
                                                    float* __restrict__ stats)
{
    __shared__ float smem[64][4][12];
    __shared__ float rs[8];
    __shared__ float sc[64], sh[64];
    int b = blockIdx.x >> 2, rh = blockIdx.x & 3;
    int t = threadIdx.x;
    if (t < 8) rs[t] = 0.f;
    if (t < 64) {
        const float invN = 1.0f / 1048576.0f;
        float var = 0.f;
        #pragma unroll
        for (int g = 0; g < 4; g++) {
            float S = stats[8 + g], Q = stats[12 + g];
            var += Q - S * S * invN;
        }
        var *= invN;
        float inv = 1.0f / sqrtf(var + 1e-5f);
        float scale = bn2g[t & 15] * inv;
        sc[t] = scale;
        sh[t] = bn2b[t] - stats[8 + (t >> 4)] * invN * scale;
    }
    __syncthreads();
    for (int i = t; i < 3072; i += 256) {
        int ic = i / 48, rem = i % 48, r = rem / 12, cc = rem % 12;
        int gr = rh * 2 - 1 + r, gc = cc - 1;
        float v = 0.f;
        if (gr >= 0 && gr < 8 && gc >= 0 && gc < 8) {
            const float* base = out2 + ((size_t)(b * 64 + ic) * 16 + 2 * gr) * 16 + 2 * gc;
            float2 a = *reinterpret_cast<const float2*>(base);
            float2 d = *reinterpret_cast<const float2*>(base + 16);
            float s0 = sc[ic], s1 = sh[ic];
            v = 0.25f * (fmaxf(fmaf(a.x, s0, s1), 0.f) + fmaxf(fmaf(a.y, s0, s1), 0.f)
                       + fmaxf(fmaf(d.x, s0, s1), 0.f) + fmaxf(fmaf(d.y, s0, s1), 0.f));
        }
        smem[ic][r][cc] = v;
    }
    __syncthreads();

    int oc = t & 127, rp = t >> 7;
    float bb = b3[oc];
    float acc[8];
    #pragma unroll
    for (int px = 0; px < 8; px++) acc[px] = bb;

    const float* Wp = W3 + oc;
    float w[9], wn[9];
    #pragma unroll
    for (int k = 0; k < 9; k++) w[k] = Wp[k * 128];
    for (int ic = 0; ic < 64; ic++) {
        if (ic < 63) {
            #pragma unroll
            for (int k = 0; k < 9; k++) wn[k] = Wp[(ic + 1) * 1152 + k * 128];
        }
        float rowv[3][12];
        #pragma unroll
        for (int dy = 0; dy < 3; dy++) {
            const float* rb = &smem[ic][rp + dy][0];
            float4 a = *reinterpret_cast<const float4*>(rb);
            float4 bq = *reinterpret_cast<const float4*>(rb + 4);
            float4 cq = *reinterpret_cast<const float4*>(rb + 8);
            rowv[dy][0]=a.x;  rowv[dy][1]=a.y;  rowv[dy][2]=a.z;  rowv[dy][3]=a.w;
            rowv[dy][4]=bq.x; rowv[dy][5]=bq.y; rowv[dy][6]=bq.z; rowv[dy][7]=bq.w;
            rowv[dy][8]=cq.x; rowv[dy][9]=cq.y; rowv[dy][10]=cq.z; rowv[dy][11]=cq.w;
        }
        #pragma unroll
        for (int dy = 0; dy < 3; dy++)
            #pragma unroll
            for (int px = 0; px < 8; px++) {
                float a = acc[px];
                a = fmaf(w[dy*3+0], rowv[dy][px],   a);
                a = fmaf(w[dy*3+1], rowv[dy][px+1], a);
                a = fmaf(w[dy*3+2], rowv[dy][px+2], a);
                acc[px] = a;
            }
        if (ic < 63) {
            #pragma unroll
            for (int k = 0; k < 9; k++) w[k] = wn[k];
        }
    }
    int row = rh * 2 + rp;
    float* outb = out3 + ((size_t)b * 128 + oc) * 64 + row * 8;
    *reinterpret_cast<float4*>(outb)     = make_float4(acc[0], acc[1], acc[2], acc[3]);
    *reinterpret_cast<float4*>(outb + 4) = make_float4(acc[4], acc[5], acc[6], acc[7]);
    float sv = 0.f, qv = 0.f;
    #pragma unroll
    for (int px = 0; px < 8; px++) { sv += acc[px]; qv += acc[px] * acc[px]; }
    int g = oc >> 5;
    atomicAdd(&rs[g], sv); atomicAdd(&rs[4 + g], qv);
    __syncthreads();
    if (t < 8) atomicAdd(&stats[16 + t], rs[t]);
}

// ---------------- fc (+fused bn3/relu/pool staging): [256,2048]@[2048,16]+b ----
__global__ __launch_bounds__(256) void fc_kernel(const float* __restrict__ out3,
                                                 const float* __restrict__ WFC,
                                                 const float* __restrict__ fcb,
                                                 const float* __restrict__ bn3g,
                                                 const float* __restrict__ bn3b,
                                                 const float* __restrict__ stats,
                                                 float* __restrict__ out)
{
    __shared__ float p3s[2048];
    __shared__ float sc[128], sh[128];
    __shared__ float red[256];
    int b = blockIdx.x, t = threadIdx.x;
    if (t < 128) {
        const float invN = 1.0f / 524288.0f;
        float var = 0.f;
        #pragma unroll
        for (int g = 0; g < 4; g++) {
            float S = stats[16 + g], Q = stats[20 + g];
            var += Q - S * S * invN;
        }
        var *= invN;
        float inv = 1.0f / sqrtf(var + 1e-5f);
        float scale = bn3g[t & 31] * inv;
        sc[t] = scale;
        sh[t] = bn3b[t] - stats[16 + (t >> 5)] * invN * scale;
    }
    __syncthreads();
    for (int i = t; i < 2048; i += 256) {
        int c = i >> 4, rem = i & 15, pr = rem >> 2, pc = rem & 3;
        const float* base = out3 + ((size_t)(b * 128 + c) * 8 + 2 * pr) * 8 + 2 * pc;
        float2 a = *reinterpret_cast<const float2*>(base);
        float2 d = *reinterpret_cast<const float2*>(base + 8);
        float s0 = sc[c], s1 = sh[c];
        p3s[i] = 0.25f * (fmaxf(fmaf(a.x, s0, s1), 0.f) + fmaxf(fmaf(a.y, s0, s1), 0.f)
                        + fmaxf(fmaf(d.x, s0, s1), 0.f) + fmaxf(fmaf(d.y, s0, s1), 0.f));
    }
    __syncthreads();
    int col = t & 15, fr = t >> 4;
    float s = 0.f;
    for (int i = 0; i < 128; i++) {
        int f = i * 16 + fr;
        s = fmaf(p3s[f], WFC[f * 16 + col], s);
    }
    red[t] = s;
    __syncthreads();
    for (int st = 128; st >= 16; st >>= 1) {
        if (t < st) red[t] += red[t + st];
        __syncthreads();
    }
    if (t < 16) out[b * 16 + t] = red[t] + fcb[t];
}

// ---------------- launch ----------------
extern "C" void kernel_launch(void* const* d_in, const int* in_sizes, int n_in,
                              void* d_out, int out_size, void* d_ws, size_t ws_size,
                              hipStream_t stream)
{
    (void)in_sizes; (void)n_in; (void)out_size; (void)ws_size;
    const float* x     = (const float*)d_in[0];
    const float* w_eca = (const float*)d_in[1];
    const float* l1r = (const float*)d_in[2],  *l1i = (const float*)d_in[3];
    const float* l1j = (const float*)d_in[4],  *l1k = (const float*)d_in[5];
    const float* l1b = (const float*)d_in[6];
    const float* bn1g = (const float*)d_in[7], *bn1b = (const float*)d_in[8];
    const float* l2r = (const float*)d_in[9],  *l2i = (const float*)d_in[10];
    const float* l2j = (const float*)d_in[11], *l2k = (const float*)d_in[12];
    const float* l2b = (const float*)d_in[13];
    const float* bn2g = (const float*)d_in[14], *bn2b = (const float*)d_in[15];
    const float* l3r = (const float*)d_in[16], *l3i = (const float*)d_in[17];
    const float* l3j = (const float*)d_in[18], *l3k = (const float*)d_in[19];
    const float* l3b = (const float*)d_in[20];
    const float* bn3g = (const float*)d_in[21], *bn3b = (const float*)d_in[22];
    const float* fcr = (const float*)d_in[23], *fci = (const float*)d_in[24];
    const float* fcj = (const float*)d_in[25], *fck = (const float*)d_in[26];
    const float* fcb = (const float*)d_in[27];

    float* ws   = (float*)d_ws;
    float* outp = (float*)d_out;

    prepmean_kernel<<<1024, 256, 0, stream>>>(x, ws + WS_POOL,
        l1r, l1i, l1j, l1k, l2r, l2i, l2j, l2k, l3r, l3i, l3j, l3k,
        fcr, fci, fcj, fck, ws);
    conv1_kernel<<<2048, 256, 0, stream>>>(x, ws + WS_POOL, w_eca, ws + WS_W1,
                                           l1b, ws + WS_OUT1, ws + WS_STATS);
    conv2_kernel<<<2048, 256, 0, stream>>>(ws + WS_OUT1, ws + WS_W2, l2b, bn1g, bn1b,
                                           ws + WS_OUT2, ws + WS_STATS);
    conv3_kernel<<<1024, 256, 0, stream>>>(ws + WS_OUT2, ws + WS_W3, l3b, bn2g, bn2b,
                                           ws + WS_OUT3, ws + WS_STATS);
    fc_kernel<<<256, 256, 0, stream>>>(ws + WS_OUT3, ws + WS_WFC, fcb, bn3g, bn3b,
                                       ws + WS_STATS, outp);
}